// Round 11
// baseline (317.985 us; speedup 1.0000x reference)
//
#include <hip/hip_runtime.h>
#include <math.h>

#define PI_F 3.14159265358979323846f

typedef __attribute__((ext_vector_type(8))) short short8v;   // 8 bf16 (4 VGPRs)
typedef __attribute__((ext_vector_type(4))) float f32x4;     // MFMA accumulator

// broadcast lane l's value of v to all lanes (v_readlane -> SGPR)
__device__ __forceinline__ float lane_bcast(float v, int l) {
  return __int_as_float(__builtin_amdgcn_readlane(__float_as_int(v), l));
}

// float -> bf16 (round to nearest even)
__device__ __forceinline__ unsigned short f2bf(float f) {
  unsigned u = __float_as_uint(f);
  unsigned r = u + 0x7FFFu + ((u >> 16) & 1u);
  return (unsigned short)(r >> 16);
}

// ---------------- wave reduce ----------------
__device__ __forceinline__ float wave_reduce_sum(float v) {
  v += __shfl_xor(v, 32, 64);
  v += __shfl_xor(v, 16, 64);
  v += __shfl_xor(v, 8, 64);
  v += __shfl_xor(v, 4, 64);
  v += __shfl_xor(v, 2, 64);
  v += __shfl_xor(v, 1, 64);
  return v;
}

// ---------------- LayerNorm -> bf16 output; fused W cast ----------------
__global__ __launch_bounds__(256) void ln_kernel(const float* __restrict__ x,
    const float* __restrict__ w, const float* __restrict__ b,
    const float* __restrict__ ipw, unsigned short* __restrict__ obf,
    unsigned short* __restrict__ wbf) {
  int row = blockIdx.x * 4 + (threadIdx.x >> 6);
  int lane = threadIdx.x & 63;
  const float* xr = x + (size_t)row * 192;
  float v0 = xr[lane], v1 = xr[lane + 64], v2 = xr[lane + 128];
  float s  = wave_reduce_sum(v0 + v1 + v2);
  float s2 = wave_reduce_sum(v0 * v0 + v1 * v1 + v2 * v2);
  float mu  = s * (1.f / 192.f);
  float var = s2 * (1.f / 192.f) - mu * mu;
  float rs  = rsqrtf(var + 1e-5f);
  unsigned short* orow = obf + (size_t)row * 192;
  orow[lane]       = f2bf((v0 - mu) * rs * w[lane]       + b[lane]);
  orow[lane + 64]  = f2bf((v1 - mu) * rs * w[lane + 64]  + b[lane + 64]);
  orow[lane + 128] = f2bf((v2 - mu) * rs * w[lane + 128] + b[lane + 128]);
  // fused cast of in_proj_w (147456 = 1024 blocks * 144)
  for (int i = threadIdx.x; i < 144; i += 256) {
    int idx = blockIdx.x * 144 + i;
    wbf[idx] = f2bf(ipw[idx]);
  }
}

// ---------------- MFMA bf16 GEMM: xz = A(4096x192) @ W(768x192)^T -----------
__global__ __launch_bounds__(256) void gemm_mfma_in(
    const unsigned short* __restrict__ Abf, const unsigned short* __restrict__ Wbf,
    float* __restrict__ C) {
  int wave = threadIdx.x >> 6;
  int lane = threadIdx.x & 63;
  int m0 = blockIdx.y * 64 + wave * 16;
  int n0 = blockIdx.x * 64;
  int rw = lane & 15;
  int g  = lane >> 4;
  const unsigned short* Ap = Abf + (size_t)(m0 + rw) * 192 + g * 8;
  const unsigned short* Wp = Wbf + (size_t)(n0 + rw) * 192 + g * 8;
  f32x4 acc[4];
#pragma unroll
  for (int f = 0; f < 4; ++f) acc[f] = (f32x4){0.f, 0.f, 0.f, 0.f};
#pragma unroll
  for (int kk = 0; kk < 192; kk += 32) {
    short8v a = *(const short8v*)(Ap + kk);
#pragma unroll
    for (int f = 0; f < 4; ++f) {
      short8v bfr = *(const short8v*)(Wp + (size_t)f * 16 * 192 + kk);
      acc[f] = __builtin_amdgcn_mfma_f32_16x16x32_bf16(a, bfr, acc[f], 0, 0, 0);
    }
  }
#pragma unroll
  for (int f = 0; f < 4; ++f)
#pragma unroll
    for (int r = 0; r < 4; ++r)
      C[(size_t)(m0 + g * 4 + r) * 768 + n0 + f * 16 + rw] = acc[f][r];
}

// ---------------- MFMA bf16 GEMM: dbc = xc(4096x384) @ x_proj_w(140x384)^T --
__global__ __launch_bounds__(256) void gemm_mfma_xp(
    const unsigned short* __restrict__ Abf, const unsigned short* __restrict__ Wbf,
    float* __restrict__ C) {
  int wave = threadIdx.x >> 6;
  int lane = threadIdx.x & 63;
  int m0 = blockIdx.y * 64 + wave * 16;
  int n0 = blockIdx.x * 64;
  int rw = lane & 15;
  int g  = lane >> 4;
  const unsigned short* Ap = Abf + (size_t)(m0 + rw) * 384 + g * 8;
  f32x4 acc[4];
#pragma unroll
  for (int f = 0; f < 4; ++f) acc[f] = (f32x4){0.f, 0.f, 0.f, 0.f};
  short8v bz = {0, 0, 0, 0, 0, 0, 0, 0};
#pragma unroll
  for (int kk = 0; kk < 384; kk += 32) {
    short8v a = *(const short8v*)(Ap + kk);
#pragma unroll
    for (int f = 0; f < 4; ++f) {
      int n = n0 + f * 16 + rw;
      short8v bfr = (n < 140)
        ? *(const short8v*)(Wbf + (size_t)n * 384 + g * 8 + kk) : bz;
      acc[f] = __builtin_amdgcn_mfma_f32_16x16x32_bf16(a, bfr, acc[f], 0, 0, 0);
    }
  }
#pragma unroll
  for (int f = 0; f < 4; ++f)
#pragma unroll
    for (int r = 0; r < 4; ++r) {
      int n = n0 + f * 16 + rw;
      if (n < 140)
        C[(size_t)(m0 + g * 4 + r) * 140 + n] = acc[f][r];
    }
}

// ---------------- MFMA bf16 GEMM with k-major A (LDS transpose) -------------
__global__ __launch_bounds__(256) void gemm_at32m(const float* __restrict__ AT,
    const unsigned short* __restrict__ Wbf, const float* __restrict__ res,
    float* __restrict__ C) {
  __shared__ unsigned As[64][17];   // [m][k-pair], stride 17 => bank-conflict-free
  int tid = threadIdx.x;
  int wave = tid >> 6, lane = tid & 63;
  int n0 = blockIdx.x * 64;         // 0,64,128
  int m0 = blockIdx.y * 64;         // 64 blocks
  int bb = m0 >> 10;
  int t0 = m0 & 1023;
  const float* Ab = AT + ((size_t)bb * 384) * 1024 + t0;
  int col = tid & 63;               // m within tile (t)
  int kq  = tid >> 6;               // 0..3 (k-pair group)
  int rw = lane & 15, g = lane >> 4;
  f32x4 acc[4];
#pragma unroll
  for (int f = 0; f < 4; ++f) acc[f] = (f32x4){0.f, 0.f, 0.f, 0.f};
#pragma unroll
  for (int kk = 0; kk < 384; kk += 32) {
#pragma unroll
    for (int p = 0; p < 4; ++p) {
      int k2 = kq + p * 4;                       // u32 index 0..15
      int k = kk + k2 * 2;
      float f0 = Ab[(size_t)k * 1024 + col];
      float f1 = Ab[(size_t)(k + 1) * 1024 + col];
      As[col][k2] = (unsigned)f2bf(f0) | ((unsigned)f2bf(f1) << 16);
    }
    __syncthreads();
    int mrow = wave * 16 + rw;
    unsigned u0 = As[mrow][g * 4 + 0];
    unsigned u1 = As[mrow][g * 4 + 1];
    unsigned u2 = As[mrow][g * 4 + 2];
    unsigned u3 = As[mrow][g * 4 + 3];
    short8v a;
    ((unsigned*)&a)[0] = u0; ((unsigned*)&a)[1] = u1;
    ((unsigned*)&a)[2] = u2; ((unsigned*)&a)[3] = u3;
#pragma unroll
    for (int f = 0; f < 4; ++f) {
      short8v bfr = *(const short8v*)(Wbf + (size_t)(n0 + f * 16 + rw) * 384 + kk + g * 8);
      acc[f] = __builtin_amdgcn_mfma_f32_16x16x32_bf16(a, bfr, acc[f], 0, 0, 0);
    }
    __syncthreads();
  }
#pragma unroll
  for (int f = 0; f < 4; ++f)
#pragma unroll
    for (int r = 0; r < 4; ++r) {
      int m = m0 + wave * 16 + g * 4 + r;
      int n = n0 + f * 16 + rw;
      C[(size_t)m * 192 + n] = acc[f][r] + res[(size_t)m * 192 + n];
    }
}

// ---------------- transposing LayerNorm: writes x2T[(Bi*192+ch)*1024 + n] ----
__global__ __launch_bounds__(256) void ln2t_kernel(const float* __restrict__ x,
    const float* __restrict__ w, const float* __restrict__ b, float* __restrict__ xT) {
  __shared__ float xt[32][193];
  __shared__ float mu_s[32], rs_s[32];
  int blk = blockIdx.x;            // 128 blocks
  int Bi = blk >> 5;
  int t0 = (blk & 31) * 32;
  int tid = threadIdx.x;
  const float* xb = x + ((size_t)(Bi * 1024 + t0)) * 192;
  for (int i = tid; i < 32 * 192; i += 256) {
    xt[i / 192][i % 192] = xb[i];
  }
  __syncthreads();
  int row = tid >> 3, seg = tid & 7;
  float s = 0.f, s2 = 0.f;
  const float* xr = &xt[row][seg * 24];
#pragma unroll
  for (int k = 0; k < 24; ++k) { float v = xr[k]; s += v; s2 += v * v; }
  s  += __shfl_xor(s, 1, 64);  s  += __shfl_xor(s, 2, 64);  s  += __shfl_xor(s, 4, 64);
  s2 += __shfl_xor(s2, 1, 64); s2 += __shfl_xor(s2, 2, 64); s2 += __shfl_xor(s2, 4, 64);
  if (seg == 0) {
    float mu = s * (1.f / 192.f);
    float var = s2 * (1.f / 192.f) - mu * mu;
    mu_s[row] = mu;
    rs_s[row] = rsqrtf(var + 1e-5f);
  }
  __syncthreads();
  for (int i = tid; i < 32 * 192; i += 256) {
    int ch = i >> 5, r2 = i & 31;
    float v = (xt[r2][ch] - mu_s[r2]) * rs_s[r2] * w[ch] + b[ch];
    xT[((size_t)(Bi * 192 + ch)) * 1024 + t0 + r2] = v;
  }
}

// ---------------- causal depthwise conv1d(k=4) + SiLU + bf16 copy ----------
__global__ __launch_bounds__(256) void conv_silu(const float* __restrict__ xz,
    const float* __restrict__ cw, const float* __restrict__ cb,
    float* __restrict__ xc, unsigned short* __restrict__ xcbf,
    const float* __restrict__ xpw, unsigned short* __restrict__ xpwbf) {
  // fused cast of x_proj_w (53760 = 1536 blocks * 35)
  if (threadIdx.x < 35) {
    int ci = blockIdx.x * 35 + threadIdx.x;
    xpwbf[ci] = f2bf(xpw[ci]);
  }
  int e4 = blockIdx.x * 256 + threadIdx.x;   // [0, 393216)
  if (e4 >= 4 * 1024 * 96) return;
  int d4 = e4 % 96;
  int t  = (e4 / 96) % 1024;
  int b  = e4 / (96 * 1024);
  int d = d4 * 4;
  const float* base = xz + (size_t)(b * 1024) * 768 + d;
  float4 acc = *(const float4*)(cb + d);
  const float4* cwv = (const float4*)(cw + d * 4);
  float4 c0 = cwv[0], c1 = cwv[1], c2 = cwv[2], c3 = cwv[3];
#pragma unroll
  for (int j = 0; j < 4; ++j) {
    int tt = t - 3 + j;
    if (tt >= 0) {
      float4 v = *(const float4*)(base + (size_t)tt * 768);
      float w0 = (&c0.x)[j], w1 = (&c1.x)[j], w2 = (&c2.x)[j], w3 = (&c3.x)[j];
      acc.x = fmaf(v.x, w0, acc.x);
      acc.y = fmaf(v.y, w1, acc.y);
      acc.z = fmaf(v.z, w2, acc.z);
      acc.w = fmaf(v.w, w3, acc.w);
    }
  }
  float4 o;
  o.x = acc.x / (1.f + __expf(-acc.x));
  o.y = acc.y / (1.f + __expf(-acc.y));
  o.z = acc.z / (1.f + __expf(-acc.z));
  o.w = acc.w / (1.f + __expf(-acc.w));
  size_t idx = ((size_t)(b * 1024 + t) * 384) + d;
  *(float4*)(xc + idx) = o;
  uint2 pk;
  pk.x = (unsigned)f2bf(o.x) | ((unsigned)f2bf(o.y) << 16);
  pk.y = (unsigned)f2bf(o.z) | ((unsigned)f2bf(o.w) << 16);
  *(uint2*)(xcbf + idx) = pk;
}

// ---------------- delta + transpose: dltT[b,d,t], duT[b,d,t] = dlt*xc ------
// Also casts out_proj_w to bf16 (384 blocks * 192 = 73728).
__global__ __launch_bounds__(256) void delta_trans(const float* __restrict__ dbc,
    const float* __restrict__ dtw, const float* __restrict__ dtb,
    const float* __restrict__ xc, float* __restrict__ dltT, float* __restrict__ duT,
    const float* __restrict__ opw, unsigned short* __restrict__ opwbf) {
  __shared__ float dts[64][13];
  __shared__ float xt[64][65];
  int blk = blockIdx.x;           // 4 * 16 * 6 = 384
  int b  = blk / 96;
  int rem = blk % 96;
  int tt = rem / 6, dd = rem % 6;
  int t0 = tt * 64, d0 = dd * 64;
  int tid = threadIdx.x;
  for (int i = tid; i < 192; i += 256) {
    int idx = blk * 192 + i;
    opwbf[idx] = f2bf(opw[idx]);
  }
  for (int i = tid; i < 64 * 12; i += 256) {
    int tl = i / 12, r = i % 12;
    dts[tl][r] = dbc[((size_t)b * 1024 + t0 + tl) * 140 + r];
  }
  {
    int col = tid & 63, rg = tid >> 6;
#pragma unroll
    for (int j = 0; j < 16; ++j) {
      int row = j * 4 + rg;
      xt[row][col] = xc[((size_t)b * 1024 + t0 + row) * 384 + d0 + col];
    }
  }
  __syncthreads();
  int tl = tid & 63, grp = tid >> 6;
#pragma unroll
  for (int j = 0; j < 16; ++j) {
    int dl = grp * 16 + j;
    int d = d0 + dl;
    float s = dtb[d];
#pragma unroll
    for (int r = 0; r < 12; ++r) s += dts[tl][r] * dtw[d * 12 + r];
    float dlt = (s > 20.f) ? s : log1pf(__expf(s));
    size_t ob = ((size_t)b * 384 + d) * 1024 + t0 + tl;
    dltT[ob] = dlt;
    duT[ob]  = dlt * xt[tl][dl];
  }
}

// ---------------- SHARED-B/C selective scan: 6 waves (6 d's) per block ------
// B/C depend only on (b,t) -- NOT d. Previous scans had all 384 waves per b
// redundantly load the same B/C rows (the measured ~3200 stall-cyc/group).
// Now one block = 6 consecutive d of the same b (256 blocks = 1536 waves,
// 1 block/CU): the 384 threads cooperatively stage the group's shared 8KB
// B/C tile into double-buffered LDS ONCE (6x fewer global loads), issued
// before the ~900cy compute phase so latency hides; one barrier per group
// publishes the buffer. Per-wave recurrence identical (bit-exact numerics).
__global__ __launch_bounds__(384, 1) void scan_shared(const float* __restrict__ dltT,
    const float* __restrict__ duT, const float* __restrict__ dbc,
    const float* __restrict__ A_log, const float* __restrict__ xc,
    const float* __restrict__ xz, const float* __restrict__ Dvec,
    float* __restrict__ yT) {
  __shared__ float Bs[2][16][64];     // 8KB  (shared across the 6 waves)
  __shared__ float Cs[2][16][64];     // 8KB
  __shared__ float tile[6][16][65];   // 24.4KB (per-wave reduce scratch)
  int blk = blockIdx.x;               // 256 = 4 b * 64
  int b = blk >> 6;
  int d0 = (blk & 63) * 6;
  int tid = threadIdx.x;
  int w = tid >> 6;                   // wave 0..5 -> d = d0 + w
  int lane = tid & 63;                // state index n
  int d = d0 + w;
  float A = -__expf(A_log[d * 64 + lane]) * 1.44269504f;
  const float* dT = dltT + ((size_t)b * 384 + d) * 1024;
  const float* uT = duT  + ((size_t)b * 384 + d) * 1024;
  const float* Bg = dbc + (size_t)(b * 1024) * 140 + 12;  // + t*140 + n
  float ddv = Dvec[d];
  float* yp = yT + ((size_t)b * 384 + d) * 1024;
  const float* xcp = xc + (size_t)(b * 1024) * 384 + d;
  const float* xzp = xz + (size_t)(b * 1024) * 768 + 384 + d;
  int tq = lane & 15, q = lane >> 4;
  // cooperative staging indices: 1024 elems each of B,C over 384 threads
  int i0 = tid, i1 = tid + 384, i2 = tid + 768;      // i0,i1 always valid
  size_t o0 = (size_t)(i0 >> 6) * 140 + (i0 & 63);
  size_t o1 = (size_t)(i1 >> 6) * 140 + (i1 & 63);
  size_t o2 = (size_t)(i2 >> 6) * 140 + (i2 & 63);
  bool has2 = (i2 < 1024);

  // ---- prologue: stage group 0 into buf 0 ----
  {
    float b0 = Bg[o0], c0 = Bg[o0 + 64];
    float b1 = Bg[o1], c1 = Bg[o1 + 64];
    float b2 = 0.f, c2 = 0.f;
    if (has2) { b2 = Bg[o2]; c2 = Bg[o2 + 64]; }
    Bs[0][i0 >> 6][i0 & 63] = b0;  Cs[0][i0 >> 6][i0 & 63] = c0;
    Bs[0][i1 >> 6][i1 & 63] = b1;  Cs[0][i1 >> 6][i1 & 63] = c1;
    if (has2) { Bs[0][i2 >> 6][i2 & 63] = b2;  Cs[0][i2 >> 6][i2 & 63] = c2; }
  }
  float h = 0.f;
  float dv64 = dT[lane], du64 = uT[lane];
  float xcv = 0.f, zv = 0.f;
  if (lane < 16) {
    xcv = xcp[(size_t)lane * 384];
    zv  = xzp[(size_t)lane * 768];
  }
  __syncthreads();

  for (int g = 0; g < 64; ++g) {
    int cur = g & 1, nxt = cur ^ 1;
    // ---- stage group g+1 (loads batched first, writes after) ----
    if (g + 1 < 64) {
      const float* Bg1 = Bg + (size_t)(g + 1) * (16 * 140);
      float b0 = Bg1[o0], c0 = Bg1[o0 + 64];
      float b1 = Bg1[o1], c1 = Bg1[o1 + 64];
      float b2 = 0.f, c2 = 0.f;
      if (has2) { b2 = Bg1[o2]; c2 = Bg1[o2 + 64]; }
      Bs[nxt][i0 >> 6][i0 & 63] = b0;  Cs[nxt][i0 >> 6][i0 & 63] = c0;
      Bs[nxt][i1 >> 6][i1 & 63] = b1;  Cs[nxt][i1 >> 6][i1 & 63] = c1;
      if (has2) { Bs[nxt][i2 >> 6][i2 & 63] = b2;  Cs[nxt][i2 >> 6][i2 & 63] = c2; }
    }
    // ---- prefetch next gates / per-segment dv,du ----
    float xcvN = 0.f, zvN = 0.f, dvN = dv64, duN = du64;
    if (g + 1 < 64) {
      int ts1 = (g + 1) * 16;
      if (lane < 16) {
        xcvN = xcp[(size_t)(ts1 + lane) * 384];
        zvN  = xzp[(size_t)(ts1 + lane) * 768];
      }
      if (((g + 1) & 3) == 0) {
        int sg = (g + 1) >> 2;
        dvN = dT[sg * 64 + lane];
        duN = uT[sg * 64 + lane];
      }
    }
    // ---- compute group g from LDS[cur] ----
    int tb = (g & 3) * 16;
    float Bv[16], Cv[16];
#pragma unroll
    for (int i = 0; i < 16; ++i) {
      Bv[i] = Bs[cur][i][lane];
      Cv[i] = Cs[cur][i][lane];
    }
#pragma unroll
    for (int i = 0; i < 16; ++i) {
      float sdv = lane_bcast(dv64, tb + i);
      float sdu = lane_bcast(du64, tb + i);
      float a = exp2f(sdv * A);
      h = fmaf(h, a, sdu * Bv[i]);
      tile[w][i][lane] = h * Cv[i];
    }
    // y[t] = sum_n tile[w][t][n]; same-wave LDS RAW -> lgkmcnt handles it
    const float* trow = &tile[w][tq][q * 16];
    float s_ = 0.f;
#pragma unroll
    for (int i = 0; i < 16; ++i) s_ += trow[i];
    s_ += __shfl_xor(s_, 16, 64);
    s_ += __shfl_xor(s_, 32, 64);
    if (lane < 16) {
      float sg2 = zv / (1.f + __expf(-zv));
      yp[g * 16 + lane] = (s_ + xcv * ddv) * sg2;
    }
    xcv = xcvN; zv = zvN; dv64 = dvN; du64 = duN;
    __syncthreads();   // publish staged buffer; orders next group's reads
  }
}

// ---------------- radix-4 1024-pt FFT in LDS ----------------
__device__ __forceinline__ int rev4_10(int i) {
  unsigned r = __brev((unsigned)i) >> 22;
  return (int)(((r & 0x155u) << 1) | ((r >> 1) & 0x155u));
}

__device__ __forceinline__ void fft1024r4(float* __restrict__ re,
    float* __restrict__ im, const float* __restrict__ twc,
    const float* __restrict__ tws, int tid, float sgn) {
  for (int i = tid; i < 1024; i += 256) {
    int r = rev4_10(i);
    if (i < r) {
      float t = re[i]; re[i] = re[r]; re[r] = t;
      t = im[i]; im[i] = im[r]; im[r] = t;
    }
  }
  __syncthreads();
  {
    float4 ar = *(float4*)&re[tid * 4];
    float4 ai = *(float4*)&im[tid * 4];
    float apc_r = ar.x + ar.z, amc_r = ar.x - ar.z;
    float apc_i = ai.x + ai.z, amc_i = ai.x - ai.z;
    float bpd_r = ar.y + ar.w, bmd_r = ar.y - ar.w;
    float bpd_i = ai.y + ai.w, bmd_i = ai.y - ai.w;
    float4 yr, yi;
    yr.x = apc_r + bpd_r;        yi.x = apc_i + bpd_i;
    yr.z = apc_r - bpd_r;        yi.z = apc_i - bpd_i;
    yr.y = amc_r - sgn * bmd_i;  yi.y = amc_i + sgn * bmd_r;
    yr.w = amc_r + sgn * bmd_i;  yi.w = amc_i - sgn * bmd_r;
    *(float4*)&re[tid * 4] = yr;
    *(float4*)&im[tid * 4] = yi;
  }
  __syncthreads();
#pragma unroll
  for (int s = 1; s < 5; ++s) {
    int L = 1 << (2 * s);
    int tstep = 256 >> (2 * s);
    int j = tid & (L - 1);
    int base = ((tid >> (2 * s)) << (2 * s + 2)) + j;
    int i0 = base, i1 = base + L, i2 = base + 2 * L, i3 = base + 3 * L;
    int x1i = j * tstep;
    float w1c = twc[x1i],     w1s = tws[x1i];
    float w2c = twc[2 * x1i], w2s = tws[2 * x1i];
    float w3c = twc[3 * x1i], w3s = tws[3 * x1i];
    float ar_ = re[i0], ai_ = im[i0];
    float br_ = re[i1], bi_ = im[i1];
    float cr_ = re[i2], ci_ = im[i2];
    float dr_ = re[i3], di_ = im[i3];
    float tbr = br_ * w1c - bi_ * w1s, tbi = br_ * w1s + bi_ * w1c;
    float tcr = cr_ * w2c - ci_ * w2s, tci = cr_ * w2s + ci_ * w2c;
    float tdr = dr_ * w3c - di_ * w3s, tdi = dr_ * w3s + di_ * w3c;
    float apc_r = ar_ + tcr, amc_r = ar_ - tcr;
    float apc_i = ai_ + tci, amc_i = ai_ - tci;
    float bpd_r = tbr + tdr, bmd_r = tbr - tdr;
    float bpd_i = tbi + tdi, bmd_i = tbi - tdi;
    re[i0] = apc_r + bpd_r;       im[i0] = apc_i + bpd_i;
    re[i2] = apc_r - bpd_r;       im[i2] = apc_i - bpd_i;
    re[i1] = amc_r - sgn * bmd_i; im[i1] = amc_i + sgn * bmd_r;
    re[i3] = amc_r + sgn * bmd_i; im[i3] = amc_i - sgn * bmd_r;
    __syncthreads();
  }
}

// forward fft2: one block per (Bi,d,c). x2T channel-major -> coalesced loads;
// X stored [(Bi*4+c)*48+d][k] -> coalesced writes.
__global__ __launch_bounds__(256) void fft_fwd(const float* __restrict__ x2T,
    float* __restrict__ Xre, float* __restrict__ Xim) {
  __shared__ float re[1024];
  __shared__ float im[1024];
  __shared__ float twc[768];
  __shared__ float tws[768];
  int blk = blockIdx.x;
  int c = blk & 3;
  int rest = blk >> 2;
  int d = rest % 48, Bi = rest / 48;
  int tid = threadIdx.x;
  for (int k = tid; k < 768; k += 256) {
    float sv, cv;
    __sincosf(-PI_F * (float)k * (1.f / 512.f), &sv, &cv);
    twc[k] = cv; tws[k] = sv;
  }
  const float* pb = x2T + ((size_t)(Bi * 192 + d)) * 1024;
  for (int n = tid; n < 1024; n += 256) {
    float v0 = pb[n];
    float v1 = pb[48 * 1024 + n];
    float v2 = pb[96 * 1024 + n];
    float v3 = pb[144 * 1024 + n];
    float rr, ii;
    if (c == 0)      { rr = v0 + v1 + v2 + v3; ii = 0.f; }
    else if (c == 1) { rr = v0 - v2;           ii = -(v1 - v3); }
    else if (c == 2) { rr = v0 - v1 + v2 - v3; ii = 0.f; }
    else             { rr = v0 - v2;           ii = (v1 - v3); }
    re[n] = rr; im[n] = ii;
  }
  __syncthreads();
  fft1024r4(re, im, twc, tws, tid, -1.0f);
  float* xo_r = Xre + ((size_t)((Bi * 4 + c) * 48 + d)) * 1024;
  float* xo_i = Xim + ((size_t)((Bi * 4 + c) * 48 + d)) * 1024;
  for (int k = tid; k < 1024; k += 256) {
    xo_r[k] = re[k] * (1.f / 64.f);
    xo_i[k] = im[k] * (1.f / 64.f);
  }
}

// ---------------- EinFFT mix, FUSED l1+l2, 4 k-rows per wave ----------------
__global__ __launch_bounds__(256) void mix_fused(float* __restrict__ Xre,
    float* __restrict__ Xim, const float* __restrict__ cw1,
    const float* __restrict__ cw2, const float* __restrict__ cb1,
    const float* __restrict__ cb2) {
  __shared__ float r1s[4][48][4];
  __shared__ float i1s[4][48][4];
  int w = threadIdx.x >> 6;
  int j = threadIdx.x & 63;
  int rg = blockIdx.x * 4 + w;       // [0, 4096)
  int kq = rg & 255;
  int b  = (rg >> 8) & 3;
  int Bi = rg >> 10;
  int k0 = kq * 4;
  size_t xbase = ((size_t)((Bi * 4 + b) * 48)) * 1024 + k0;
  if (j < 48) {
    const float* wr = cw1 + b * 2304;
    const float* wi = cw1 + 9216 + b * 2304;
    float b1r = cb1[b * 48 + j], b1i = cb1[192 + b * 48 + j];
    float ar[4] = {b1r, b1r, b1r, b1r};
    float ai[4] = {b1i, b1i, b1i, b1i};
#pragma unroll 8
    for (int dd = 0; dd < 48; ++dd) {
      float4 xr = *(const float4*)(Xre + xbase + (size_t)dd * 1024);
      float4 xi = *(const float4*)(Xim + xbase + (size_t)dd * 1024);
      float wrv = wr[dd * 48 + j], wiv = wi[dd * 48 + j];
      ar[0] = fmaf(xr.x, wrv, ar[0]); ar[0] = fmaf(-xi.x, wiv, ar[0]);
      ai[0] = fmaf(xr.x, wiv, ai[0]); ai[0] = fmaf(xi.x, wrv, ai[0]);
      ar[1] = fmaf(xr.y, wrv, ar[1]); ar[1] = fmaf(-xi.y, wiv, ar[1]);
      ai[1] = fmaf(xr.y, wiv, ai[1]); ai[1] = fmaf(xi.y, wrv, ai[1]);
      ar[2] = fmaf(xr.z, wrv, ar[2]); ar[2] = fmaf(-xi.z, wiv, ar[2]);
      ai[2] = fmaf(xr.z, wiv, ai[2]); ai[2] = fmaf(xi.z, wrv, ai[2]);
      ar[3] = fmaf(xr.w, wrv, ar[3]); ar[3] = fmaf(-xi.w, wiv, ar[3]);
      ai[3] = fmaf(xr.w, wiv, ai[3]); ai[3] = fmaf(xi.w, wrv, ai[3]);
    }
    float4 r1v, i1v;
    r1v.x = fmaxf(ar[0], 0.f); r1v.y = fmaxf(ar[1], 0.f);
    r1v.z = fmaxf(ar[2], 0.f); r1v.w = fmaxf(ar[3], 0.f);
    i1v.x = fmaxf(ai[0], 0.f); i1v.y = fmaxf(ai[1], 0.f);
    i1v.z = fmaxf(ai[2], 0.f); i1v.w = fmaxf(ai[3], 0.f);
    *(float4*)&r1s[w][j][0] = r1v;
    *(float4*)&i1s[w][j][0] = i1v;
    // same-wave LDS RAW: compiler inserts lgkmcnt wait; no barrier needed
    const float* wr2 = cw2 + b * 2304;
    const float* wi2 = cw2 + 9216 + b * 2304;
    float b2r = cb2[b * 48 + j], b2i = cb2[192 + b * 48 + j];
    float a2r[4] = {b2r, b2r, b2r, b2r};
    float a2i[4] = {b2i, b2i, b2i, b2i};
#pragma unroll 8
    for (int dd = 0; dd < 48; ++dd) {
      float4 rv = *(const float4*)&r1s[w][dd][0];
      float4 iv = *(const float4*)&i1s[w][dd][0];
      float wrv = wr2[dd * 48 + j], wiv = wi2[dd * 48 + j];
      a2r[0] = fmaf(rv.x, wrv, a2r[0]); a2r[0] = fmaf(-iv.x, wiv, a2r[0]);
      a2i[0] = fmaf(rv.x, wiv, a2i[0]); a2i[0] = fmaf(iv.x, wrv, a2i[0]);
      a2r[1] = fmaf(rv.y, wrv, a2r[1]); a2r[1] = fmaf(-iv.y, wiv, a2r[1]);
      a2i[1] = fmaf(rv.y, wiv, a2i[1]); a2i[1] = fmaf(iv.y, wrv, a2i[1]);
      a2r[2] = fmaf(rv.z, wrv, a2r[2]); a2r[2] = fmaf(-iv.z, wiv, a2r[2]);
      a2i[2] = fmaf(rv.z, wiv, a2i[2]); a2i[2] = fmaf(iv.z, wrv, a2i[2]);
      a2r[3] = fmaf(rv.w, wrv, a2r[3]); a2r[3] = fmaf(-iv.w, wiv, a2r[3]);
      a2i[3] = fmaf(rv.w, wiv, a2i[3]); a2i[3] = fmaf(iv.w, wrv, a2i[3]);
    }
    float4 zr, zi;
#pragma unroll
    for (int r = 0; r < 4; ++r) {
      float vr = a2r[r], vi = a2i[r];
      (&zr.x)[r] = (vr > 0.01f) ? vr - 0.01f : ((vr < -0.01f) ? vr + 0.01f : 0.f);
      (&zi.x)[r] = (vi > 0.01f) ? vi - 0.01f : ((vi < -0.01f) ? vi + 0.01f : 0.f);
    }
    size_t obase = ((size_t)((Bi * 4 + b) * 48 + j)) * 1024 + k0;
    *(float4*)(Xre + obase) = zr;
    *(float4*)(Xim + obase) = zi;
  }
}

// inverse fft2: one block per (Bi,d,c). Z layout [(Bi*4+c')*48+d][k] ->
// coalesced reads; inline inverse 4-pt DFT, IFFT, residual, real write.
__global__ __launch_bounds__(256) void fft_inv(const float* __restrict__ Zre,
    const float* __restrict__ Zim, const float* __restrict__ x1, float* __restrict__ out) {
  __shared__ float re[1024];
  __shared__ float im[1024];
  __shared__ float twc[768];
  __shared__ float tws[768];
  int blk = blockIdx.x;
  int c = blk & 3;
  int rest = blk >> 2;
  int d = rest % 48, Bi = rest / 48;
  int tid = threadIdx.x;
  for (int k = tid; k < 768; k += 256) {
    float sv, cv;
    __sincosf(PI_F * (float)k * (1.f / 512.f), &sv, &cv);
    twc[k] = cv; tws[k] = sv;
  }
  const float* zr0 = Zre + ((size_t)((Bi * 4) * 48 + d)) * 1024;
  const float* zi0 = Zim + ((size_t)((Bi * 4) * 48 + d)) * 1024;
  const int cs = 48 * 1024;
  for (int k = tid; k < 1024; k += 256) {
    float r0 = zr0[k], r1v = zr0[cs + k], r2 = zr0[2 * cs + k], r3 = zr0[3 * cs + k];
    float i0 = zi0[k], i1v = zi0[cs + k], i2 = zi0[2 * cs + k], i3 = zi0[3 * cs + k];
    float rr, ii;
    if (c == 0)      { rr = r0 + r1v + r2 + r3;  ii = i0 + i1v + i2 + i3; }
    else if (c == 1) { rr = r0 - i1v - r2 + i3;  ii = i0 + r1v - i2 - r3; }
    else if (c == 2) { rr = r0 - r1v + r2 - r3;  ii = i0 - i1v + i2 - i3; }
    else             { rr = r0 + i1v - r2 - i3;  ii = i0 - r1v - i2 + r3; }
    re[k] = rr; im[k] = ii;
  }
  __syncthreads();
  fft1024r4(re, im, twc, tws, tid, 1.0f);
  for (int n = tid; n < 1024; n += 256) {
    size_t o = (size_t)(Bi * 1024 + n) * 192 + c * 48 + d;
    out[o] = x1[o] + re[n] * (1.f / 64.f);
  }
}

extern "C" void kernel_launch(void* const* d_in, const int* in_sizes, int n_in,
                              void* d_out, int out_size, void* d_ws, size_t ws_size,
                              hipStream_t stream) {
  const float* x         = (const float*)d_in[0];
  const float* ln1_w     = (const float*)d_in[1];
  const float* ln1_b     = (const float*)d_in[2];
  const float* in_proj_w = (const float*)d_in[3];
  const float* conv_w    = (const float*)d_in[4];
  const float* conv_b    = (const float*)d_in[5];
  const float* x_proj_w  = (const float*)d_in[6];
  const float* dt_proj_w = (const float*)d_in[7];
  const float* dt_proj_b = (const float*)d_in[8];
  const float* A_log     = (const float*)d_in[9];
  const float* Dvec      = (const float*)d_in[10];
  const float* out_proj_w= (const float*)d_in[11];
  const float* ln2_w     = (const float*)d_in[12];
  const float* ln2_b     = (const float*)d_in[13];
  const float* cw1       = (const float*)d_in[14];
  const float* cw2       = (const float*)d_in[15];
  const float* cb1       = (const float*)d_in[16];
  const float* cb2       = (const float*)d_in[17];
  float* out = (float*)d_out;
  float* ws  = (float*)d_ws;

  // workspace layout (floats). Aliases:
  //  duT = Xre+Xim region (dead until fft_fwd), dltT in dlt's slot,
  //  x1 = xln; x2T in x2's slot; xcbf lives in xln slot (dead until
  //  gemm_at32m writes x1); xpwbf in x2T slot (dead until ln2t);
  //  opwbf after wbf (fresh region).
  float* xz   = ws;                    // 3145728
  float* xc   = xz  + 3145728;         // 1572864
  float* dbc  = xc  + 1572864;         // 573440
  float* dltT = dbc + 573440;          // 1572864
  float* yvT  = dltT + 1572864;        // 1572864 (TRANSPOSED y: [b][d][t])
  float* xln  = yvT + 1572864;         // 786432
  float* x2T  = xln + 786432;          // 786432 (channel-major: [Bi*192+ch][n])
  float* Xre  = x2T + 786432;          // 786432 (layout [(Bi*4+c)*48+d][k])
  float* Xim  = Xre + 786432;          // 786432
  float* duT = Xre;                    // 1572864 (spans Xre+Xim)
  float* x1 = xln;
  unsigned short* xbf = (unsigned short*)(Xim + 786432);            // 393216 f-slots
  unsigned short* wbf = (unsigned short*)(Xim + 786432 + 393216);   // 36864 f-slots
  unsigned short* opwbf = (unsigned short*)(Xim + 786432 + 393216 + 36864); // 36864 f-slots
  unsigned short* xcbf  = (unsigned short*)xln;   // 1572864 bf16 = full xln slot
  unsigned short* xpwbf = (unsigned short*)x2T;   // 53760 bf16 (head of x2T slot)

  ln_kernel<<<1024, 256, 0, stream>>>(x, ln1_w, ln1_b, in_proj_w, xbf, wbf);
  gemm_mfma_in<<<dim3(12, 64), 256, 0, stream>>>(xbf, wbf, xz);
  conv_silu<<<1536, 256, 0, stream>>>(xz, conv_w, conv_b, xc, xcbf, x_proj_w, xpwbf);
  gemm_mfma_xp<<<dim3(3, 64), 256, 0, stream>>>(xcbf, xpwbf, dbc);
  delta_trans<<<384, 256, 0, stream>>>(dbc, dt_proj_w, dt_proj_b, xc, dltT, duT,
                                       out_proj_w, opwbf);
  scan_shared<<<256, 384, 0, stream>>>(dltT, duT, dbc, A_log, xc, xz, Dvec, yvT);
  gemm_at32m<<<dim3(3, 64), 256, 0, stream>>>(yvT, opwbf, x, x1);
  ln2t_kernel<<<128, 256, 0, stream>>>(x1, ln2_w, ln2_b, x2T);
  fft_fwd<<<768, 256, 0, stream>>>(x2T, Xre, Xim);
  mix_fused<<<1024, 256, 0, stream>>>(Xre, Xim, cw1, cw2, cb1, cb2);
  fft_inv<<<768, 256, 0, stream>>>(Xre, Xim, x1, out);
}

// Round 12
// 308.712 us; speedup vs baseline: 1.0300x; 1.0300x over previous
//
#include <hip/hip_runtime.h>
#include <math.h>

#define PI_F 3.14159265358979323846f

typedef __attribute__((ext_vector_type(8))) short short8v;   // 8 bf16 (4 VGPRs)
typedef __attribute__((ext_vector_type(4))) float f32x4;     // MFMA accumulator

// broadcast lane l's value of v to all lanes (v_readlane -> SGPR)
__device__ __forceinline__ float lane_bcast(float v, int l) {
  return __int_as_float(__builtin_amdgcn_readlane(__float_as_int(v), l));
}

// float -> bf16 (round to nearest even)
__device__ __forceinline__ unsigned short f2bf(float f) {
  unsigned u = __float_as_uint(f);
  unsigned r = u + 0x7FFFu + ((u >> 16) & 1u);
  return (unsigned short)(r >> 16);
}

// ---------------- wave reduce ----------------
__device__ __forceinline__ float wave_reduce_sum(float v) {
  v += __shfl_xor(v, 32, 64);
  v += __shfl_xor(v, 16, 64);
  v += __shfl_xor(v, 8, 64);
  v += __shfl_xor(v, 4, 64);
  v += __shfl_xor(v, 2, 64);
  v += __shfl_xor(v, 1, 64);
  return v;
}

// ---------------- FUSED LayerNorm + MFMA GEMM: xz = LN(x) @ in_proj_w^T ----
// Eliminates the standalone ln_kernel launch + xbf/wbf global round-trips.
// Each block LNs its own 64 A-rows into a padded LDS bf16 tile (12x
// redundant across n-blocks; LN is cheap), W is cast fp32->bf16 in regs at
// fragment load (L2-resident). xz numerically identical to the R8-R10 path.
// LDS tile row stride 200 bf16 = 400B = 100 dwords == 4 mod 32 banks ->
// 16-row fragment reads are 2-way conflicts (free per m136).
__global__ __launch_bounds__(256) void gemm_ln_in(const float* __restrict__ x,
    const float* __restrict__ lw, const float* __restrict__ lb,
    const float* __restrict__ W, float* __restrict__ C) {
  __shared__ unsigned short Albs[64][200];
  int tid = threadIdx.x;
  int wave = tid >> 6;
  int lane = tid & 63;
  int m0 = blockIdx.y * 64;
  int n0 = blockIdx.x * 64;
  // ---- phase 1: LN rows m0+wave*16 .. +15 into LDS (bf16) ----
  for (int i = 0; i < 16; ++i) {
    int r = wave * 16 + i;
    const float* xr = x + (size_t)(m0 + r) * 192;
    float v0 = xr[lane], v1 = xr[lane + 64], v2 = xr[lane + 128];
    float s  = wave_reduce_sum(v0 + v1 + v2);
    float s2 = wave_reduce_sum(v0 * v0 + v1 * v1 + v2 * v2);
    float mu  = s * (1.f / 192.f);
    float var = s2 * (1.f / 192.f) - mu * mu;
    float rs  = rsqrtf(var + 1e-5f);
    Albs[r][lane]       = f2bf((v0 - mu) * rs * lw[lane]       + lb[lane]);
    Albs[r][lane + 64]  = f2bf((v1 - mu) * rs * lw[lane + 64]  + lb[lane + 64]);
    Albs[r][lane + 128] = f2bf((v2 - mu) * rs * lw[lane + 128] + lb[lane + 128]);
  }
  __syncthreads();
  // ---- phase 2: MFMA (A from LDS, W cast in regs) ----
  int rw = lane & 15;
  int g  = lane >> 4;
  f32x4 acc[4];
#pragma unroll
  for (int f = 0; f < 4; ++f) acc[f] = (f32x4){0.f, 0.f, 0.f, 0.f};
#pragma unroll
  for (int kk = 0; kk < 192; kk += 32) {
    short8v a = *(const short8v*)&Albs[wave * 16 + rw][g * 8 + kk];
#pragma unroll
    for (int f = 0; f < 4; ++f) {
      const float* wp = W + (size_t)(n0 + f * 16 + rw) * 192 + kk + g * 8;
      float4 w0 = *(const float4*)wp;
      float4 w1 = *(const float4*)(wp + 4);
      short8v bfr;
      ((unsigned*)&bfr)[0] = (unsigned)f2bf(w0.x) | ((unsigned)f2bf(w0.y) << 16);
      ((unsigned*)&bfr)[1] = (unsigned)f2bf(w0.z) | ((unsigned)f2bf(w0.w) << 16);
      ((unsigned*)&bfr)[2] = (unsigned)f2bf(w1.x) | ((unsigned)f2bf(w1.y) << 16);
      ((unsigned*)&bfr)[3] = (unsigned)f2bf(w1.z) | ((unsigned)f2bf(w1.w) << 16);
      acc[f] = __builtin_amdgcn_mfma_f32_16x16x32_bf16(a, bfr, acc[f], 0, 0, 0);
    }
  }
#pragma unroll
  for (int f = 0; f < 4; ++f)
#pragma unroll
    for (int r = 0; r < 4; ++r)
      C[(size_t)(m0 + wave * 16 + g * 4 + r) * 768 + n0 + f * 16 + rw] = acc[f][r];
}

// ---------------- MFMA bf16 GEMM: dbc = xc(4096x384) @ x_proj_w(140x384)^T --
__global__ __launch_bounds__(256) void gemm_mfma_xp(
    const unsigned short* __restrict__ Abf, const unsigned short* __restrict__ Wbf,
    float* __restrict__ C) {
  int wave = threadIdx.x >> 6;
  int lane = threadIdx.x & 63;
  int m0 = blockIdx.y * 64 + wave * 16;
  int n0 = blockIdx.x * 64;
  int rw = lane & 15;
  int g  = lane >> 4;
  const unsigned short* Ap = Abf + (size_t)(m0 + rw) * 384 + g * 8;
  f32x4 acc[4];
#pragma unroll
  for (int f = 0; f < 4; ++f) acc[f] = (f32x4){0.f, 0.f, 0.f, 0.f};
  short8v bz = {0, 0, 0, 0, 0, 0, 0, 0};
#pragma unroll
  for (int kk = 0; kk < 384; kk += 32) {
    short8v a = *(const short8v*)(Ap + kk);
#pragma unroll
    for (int f = 0; f < 4; ++f) {
      int n = n0 + f * 16 + rw;
      short8v bfr = (n < 140)
        ? *(const short8v*)(Wbf + (size_t)n * 384 + g * 8 + kk) : bz;
      acc[f] = __builtin_amdgcn_mfma_f32_16x16x32_bf16(a, bfr, acc[f], 0, 0, 0);
    }
  }
#pragma unroll
  for (int f = 0; f < 4; ++f)
#pragma unroll
    for (int r = 0; r < 4; ++r) {
      int n = n0 + f * 16 + rw;
      if (n < 140)
        C[(size_t)(m0 + g * 4 + r) * 140 + n] = acc[f][r];
    }
}

// ---------------- MFMA bf16 GEMM with k-major A (LDS transpose) -------------
__global__ __launch_bounds__(256) void gemm_at32m(const float* __restrict__ AT,
    const unsigned short* __restrict__ Wbf, const float* __restrict__ res,
    float* __restrict__ C) {
  __shared__ unsigned As[64][17];   // [m][k-pair], stride 17 => bank-conflict-free
  int tid = threadIdx.x;
  int wave = tid >> 6, lane = tid & 63;
  int n0 = blockIdx.x * 64;         // 0,64,128
  int m0 = blockIdx.y * 64;         // 64 blocks
  int bb = m0 >> 10;
  int t0 = m0 & 1023;
  const float* Ab = AT + ((size_t)bb * 384) * 1024 + t0;
  int col = tid & 63;               // m within tile (t)
  int kq  = tid >> 6;               // 0..3 (k-pair group)
  int rw = lane & 15, g = lane >> 4;
  f32x4 acc[4];
#pragma unroll
  for (int f = 0; f < 4; ++f) acc[f] = (f32x4){0.f, 0.f, 0.f, 0.f};
#pragma unroll
  for (int kk = 0; kk < 384; kk += 32) {
#pragma unroll
    for (int p = 0; p < 4; ++p) {
      int k2 = kq + p * 4;                       // u32 index 0..15
      int k = kk + k2 * 2;
      float f0 = Ab[(size_t)k * 1024 + col];
      float f1 = Ab[(size_t)(k + 1) * 1024 + col];
      As[col][k2] = (unsigned)f2bf(f0) | ((unsigned)f2bf(f1) << 16);
    }
    __syncthreads();
    int mrow = wave * 16 + rw;
    unsigned u0 = As[mrow][g * 4 + 0];
    unsigned u1 = As[mrow][g * 4 + 1];
    unsigned u2 = As[mrow][g * 4 + 2];
    unsigned u3 = As[mrow][g * 4 + 3];
    short8v a;
    ((unsigned*)&a)[0] = u0; ((unsigned*)&a)[1] = u1;
    ((unsigned*)&a)[2] = u2; ((unsigned*)&a)[3] = u3;
#pragma unroll
    for (int f = 0; f < 4; ++f) {
      short8v bfr = *(const short8v*)(Wbf + (size_t)(n0 + f * 16 + rw) * 384 + kk + g * 8);
      acc[f] = __builtin_amdgcn_mfma_f32_16x16x32_bf16(a, bfr, acc[f], 0, 0, 0);
    }
    __syncthreads();
  }
#pragma unroll
  for (int f = 0; f < 4; ++f)
#pragma unroll
    for (int r = 0; r < 4; ++r) {
      int m = m0 + wave * 16 + g * 4 + r;
      int n = n0 + f * 16 + rw;
      C[(size_t)m * 192 + n] = acc[f][r] + res[(size_t)m * 192 + n];
    }
}

// ---------------- transposing LayerNorm: writes x2T[(Bi*192+ch)*1024 + n] ----
__global__ __launch_bounds__(256) void ln2t_kernel(const float* __restrict__ x,
    const float* __restrict__ w, const float* __restrict__ b, float* __restrict__ xT) {
  __shared__ float xt[32][193];
  __shared__ float mu_s[32], rs_s[32];
  int blk = blockIdx.x;            // 128 blocks
  int Bi = blk >> 5;
  int t0 = (blk & 31) * 32;
  int tid = threadIdx.x;
  const float* xb = x + ((size_t)(Bi * 1024 + t0)) * 192;
  for (int i = tid; i < 32 * 192; i += 256) {
    xt[i / 192][i % 192] = xb[i];
  }
  __syncthreads();
  int row = tid >> 3, seg = tid & 7;
  float s = 0.f, s2 = 0.f;
  const float* xr = &xt[row][seg * 24];
#pragma unroll
  for (int k = 0; k < 24; ++k) { float v = xr[k]; s += v; s2 += v * v; }
  s  += __shfl_xor(s, 1, 64);  s  += __shfl_xor(s, 2, 64);  s  += __shfl_xor(s, 4, 64);
  s2 += __shfl_xor(s2, 1, 64); s2 += __shfl_xor(s2, 2, 64); s2 += __shfl_xor(s2, 4, 64);
  if (seg == 0) {
    float mu = s * (1.f / 192.f);
    float var = s2 * (1.f / 192.f) - mu * mu;
    mu_s[row] = mu;
    rs_s[row] = rsqrtf(var + 1e-5f);
  }
  __syncthreads();
  for (int i = tid; i < 32 * 192; i += 256) {
    int ch = i >> 5, r2 = i & 31;
    float v = (xt[r2][ch] - mu_s[r2]) * rs_s[r2] * w[ch] + b[ch];
    xT[((size_t)(Bi * 192 + ch)) * 1024 + t0 + r2] = v;
  }
}

// ---------------- causal depthwise conv1d(k=4) + SiLU + bf16 copy ----------
__global__ __launch_bounds__(256) void conv_silu(const float* __restrict__ xz,
    const float* __restrict__ cw, const float* __restrict__ cb,
    float* __restrict__ xc, unsigned short* __restrict__ xcbf,
    const float* __restrict__ xpw, unsigned short* __restrict__ xpwbf) {
  // fused cast of x_proj_w (53760 = 1536 blocks * 35)
  if (threadIdx.x < 35) {
    int ci = blockIdx.x * 35 + threadIdx.x;
    xpwbf[ci] = f2bf(xpw[ci]);
  }
  int e4 = blockIdx.x * 256 + threadIdx.x;   // [0, 393216)
  if (e4 >= 4 * 1024 * 96) return;
  int d4 = e4 % 96;
  int t  = (e4 / 96) % 1024;
  int b  = e4 / (96 * 1024);
  int d = d4 * 4;
  const float* base = xz + (size_t)(b * 1024) * 768 + d;
  float4 acc = *(const float4*)(cb + d);
  const float4* cwv = (const float4*)(cw + d * 4);
  float4 c0 = cwv[0], c1 = cwv[1], c2 = cwv[2], c3 = cwv[3];
#pragma unroll
  for (int j = 0; j < 4; ++j) {
    int tt = t - 3 + j;
    if (tt >= 0) {
      float4 v = *(const float4*)(base + (size_t)tt * 768);
      float w0 = (&c0.x)[j], w1 = (&c1.x)[j], w2 = (&c2.x)[j], w3 = (&c3.x)[j];
      acc.x = fmaf(v.x, w0, acc.x);
      acc.y = fmaf(v.y, w1, acc.y);
      acc.z = fmaf(v.z, w2, acc.z);
      acc.w = fmaf(v.w, w3, acc.w);
    }
  }
  float4 o;
  o.x = acc.x / (1.f + __expf(-acc.x));
  o.y = acc.y / (1.f + __expf(-acc.y));
  o.z = acc.z / (1.f + __expf(-acc.z));
  o.w = acc.w / (1.f + __expf(-acc.w));
  size_t idx = ((size_t)(b * 1024 + t) * 384) + d;
  *(float4*)(xc + idx) = o;
  uint2 pk;
  pk.x = (unsigned)f2bf(o.x) | ((unsigned)f2bf(o.y) << 16);
  pk.y = (unsigned)f2bf(o.z) | ((unsigned)f2bf(o.w) << 16);
  *(uint2*)(xcbf + idx) = pk;
}

// ---------------- delta + transpose: dltT[b,d,t], duT[b,d,t] = dlt*xc ------
// Also casts out_proj_w to bf16 (384 blocks * 192 = 73728).
__global__ __launch_bounds__(256) void delta_trans(const float* __restrict__ dbc,
    const float* __restrict__ dtw, const float* __restrict__ dtb,
    const float* __restrict__ xc, float* __restrict__ dltT, float* __restrict__ duT,
    const float* __restrict__ opw, unsigned short* __restrict__ opwbf) {
  __shared__ float dts[64][13];
  __shared__ float xt[64][65];
  int blk = blockIdx.x;           // 4 * 16 * 6 = 384
  int b  = blk / 96;
  int rem = blk % 96;
  int tt = rem / 6, dd = rem % 6;
  int t0 = tt * 64, d0 = dd * 64;
  int tid = threadIdx.x;
  for (int i = tid; i < 192; i += 256) {
    int idx = blk * 192 + i;
    opwbf[idx] = f2bf(opw[idx]);
  }
  for (int i = tid; i < 64 * 12; i += 256) {
    int tl = i / 12, r = i % 12;
    dts[tl][r] = dbc[((size_t)b * 1024 + t0 + tl) * 140 + r];
  }
  {
    int col = tid & 63, rg = tid >> 6;
#pragma unroll
    for (int j = 0; j < 16; ++j) {
      int row = j * 4 + rg;
      xt[row][col] = xc[((size_t)b * 1024 + t0 + row) * 384 + d0 + col];
    }
  }
  __syncthreads();
  int tl = tid & 63, grp = tid >> 6;
#pragma unroll
  for (int j = 0; j < 16; ++j) {
    int dl = grp * 16 + j;
    int d = d0 + dl;
    float s = dtb[d];
#pragma unroll
    for (int r = 0; r < 12; ++r) s += dts[tl][r] * dtw[d * 12 + r];
    float dlt = (s > 20.f) ? s : log1pf(__expf(s));
    size_t ob = ((size_t)b * 384 + d) * 1024 + t0 + tl;
    dltT[ob] = dlt;
    duT[ob]  = dlt * xt[tl][dl];
  }
}

// ---------------- SINGLE-PASS selective scan, SOFTWARE-PIPELINED ----------
// REVERTED to the accepted plateau (R2/R10: ~93 us). Seven structures
// (2-phase TLP, reg-prefetch x2, producer-consumer, async-DMA, shared-B/C)
// bracket 93-126 us; the serial chain + per-group reduce is the floor.
#define SCAN_GBODY(G, BC, CC, XCV, ZVV, BN, CN, XCN, ZVN)                  \
  {                                                                        \
    int ts_ = (G) * 16;                                                    \
    if ((G) + 1 < 64) {                                                    \
      int tn_ = ts_ + 16;                                                  \
      _Pragma("unroll")                                                    \
      for (int i = 0; i < 16; ++i) {                                       \
        size_t ro = (size_t)(tn_ + i) * 140;                               \
        BN[i] = Bp[ro]; CN[i] = Cp[ro];                                    \
      }                                                                    \
      if (lane < 16) { XCN = xcp[(size_t)(tn_ + lane) * 384];              \
                       ZVN = xzp[(size_t)(tn_ + lane) * 768]; }            \
      if (((G) & 3) == 2) {                                                \
        int sn_ = ((G) >> 2) + 1;                                          \
        if (sn_ < 16) { dvN = dT[sn_ * 64 + lane];                         \
                        duN = uT[sn_ * 64 + lane]; }                       \
      }                                                                    \
    }                                                                      \
    int tb_ = ts_ & 63;                                                    \
    _Pragma("unroll")                                                      \
    for (int i = 0; i < 16; ++i) {                                         \
      float sdv = lane_bcast(dvC, tb_ + i);                                \
      float sdu = lane_bcast(duC, tb_ + i);                                \
      float a = exp2f(sdv * A);                                            \
      h = fmaf(h, a, sdu * BC[i]);                                         \
      tile[i][lane] = h * CC[i];                                           \
    }                                                                      \
    const float* trow_ = &tile[tq][q * 16];                                \
    float s_ = 0.f;                                                        \
    _Pragma("unroll")                                                      \
    for (int i = 0; i < 16; ++i) s_ += trow_[i];                           \
    s_ += __shfl_xor(s_, 16, 64);                                          \
    s_ += __shfl_xor(s_, 32, 64);                                          \
    if (lane < 16) {                                                       \
      float sg_ = ZVV / (1.f + __expf(-ZVV));                              \
      yp[ts_ + lane] = (s_ + XCV * ddv) * sg_;                             \
    }                                                                      \
    if (((G) & 3) == 3) { dvC = dvN; duC = duN; }                          \
  }

__global__ __launch_bounds__(64, 1) void scan_single(const float* __restrict__ dltT,
    const float* __restrict__ duT, const float* __restrict__ dbc,
    const float* __restrict__ A_log, const float* __restrict__ xc,
    const float* __restrict__ xz, const float* __restrict__ Dvec,
    float* __restrict__ yT) {
  __shared__ float tile[16][65];
  int bd = blockIdx.x;             // 1536 = 4 * 384
  int b = bd / 384, d = bd % 384;
  int lane = threadIdx.x;          // = state index n
  float A = -__expf(A_log[d * 64 + lane]) * 1.44269504f;
  const float* dT = dltT + ((size_t)b * 384 + d) * 1024;
  const float* uT = duT  + ((size_t)b * 384 + d) * 1024;
  const float* Bp = dbc + ((size_t)b * 1024) * 140 + 12 + lane;
  const float* Cp = Bp + 64;
  float ddv = Dvec[d];
  float* yp = yT + ((size_t)b * 384 + d) * 1024;
  const float* xcp = xc + ((size_t)b * 1024) * 384 + d;
  const float* xzp = xz + ((size_t)b * 1024) * 768 + 384 + d;
  int tq = lane & 15;
  int q  = lane >> 4;
  float h = 0.f;

  float Ba[16], Ca[16], Bb[16], Cb[16];
  float dvC, duC, dvN = 0.f, duN = 0.f;
  float xcA = 0.f, zvA = 0.f, xcB = 0.f, zvB = 0.f;

  // ---- prologue: seg-0 dv/du, group-0 B/C and gate loads ----
  dvC = dT[lane];
  duC = uT[lane];
#pragma unroll
  for (int i = 0; i < 16; ++i) {
    size_t ro = (size_t)i * 140;
    Ba[i] = Bp[ro];
    Ca[i] = Cp[ro];
  }
  if (lane < 16) {
    xcA = xcp[(size_t)lane * 384];
    zvA = xzp[(size_t)lane * 768];
  }

  for (int gp = 0; gp < 32; ++gp) {
    int g0 = gp * 2;
    SCAN_GBODY(g0,     Ba, Ca, xcA, zvA, Bb, Cb, xcB, zvB)
    SCAN_GBODY(g0 + 1, Bb, Cb, xcB, zvB, Ba, Ca, xcA, zvA)
  }
}

// ---------------- radix-4 1024-pt FFT in LDS ----------------
__device__ __forceinline__ int rev4_10(int i) {
  unsigned r = __brev((unsigned)i) >> 22;
  return (int)(((r & 0x155u) << 1) | ((r >> 1) & 0x155u));
}

__device__ __forceinline__ void fft1024r4(float* __restrict__ re,
    float* __restrict__ im, const float* __restrict__ twc,
    const float* __restrict__ tws, int tid, float sgn) {
  for (int i = tid; i < 1024; i += 256) {
    int r = rev4_10(i);
    if (i < r) {
      float t = re[i]; re[i] = re[r]; re[r] = t;
      t = im[i]; im[i] = im[r]; im[r] = t;
    }
  }
  __syncthreads();
  {
    float4 ar = *(float4*)&re[tid * 4];
    float4 ai = *(float4*)&im[tid * 4];
    float apc_r = ar.x + ar.z, amc_r = ar.x - ar.z;
    float apc_i = ai.x + ai.z, amc_i = ai.x - ai.z;
    float bpd_r = ar.y + ar.w, bmd_r = ar.y - ar.w;
    float bpd_i = ai.y + ai.w, bmd_i = ai.y - ai.w;
    float4 yr, yi;
    yr.x = apc_r + bpd_r;        yi.x = apc_i + bpd_i;
    yr.z = apc_r - bpd_r;        yi.z = apc_i - bpd_i;
    yr.y = amc_r - sgn * bmd_i;  yi.y = amc_i + sgn * bmd_r;
    yr.w = amc_r + sgn * bmd_i;  yi.w = amc_i - sgn * bmd_r;
    *(float4*)&re[tid * 4] = yr;
    *(float4*)&im[tid * 4] = yi;
  }
  __syncthreads();
#pragma unroll
  for (int s = 1; s < 5; ++s) {
    int L = 1 << (2 * s);
    int tstep = 256 >> (2 * s);
    int j = tid & (L - 1);
    int base = ((tid >> (2 * s)) << (2 * s + 2)) + j;
    int i0 = base, i1 = base + L, i2 = base + 2 * L, i3 = base + 3 * L;
    int x1i = j * tstep;
    float w1c = twc[x1i],     w1s = tws[x1i];
    float w2c = twc[2 * x1i], w2s = tws[2 * x1i];
    float w3c = twc[3 * x1i], w3s = tws[3 * x1i];
    float ar_ = re[i0], ai_ = im[i0];
    float br_ = re[i1], bi_ = im[i1];
    float cr_ = re[i2], ci_ = im[i2];
    float dr_ = re[i3], di_ = im[i3];
    float tbr = br_ * w1c - bi_ * w1s, tbi = br_ * w1s + bi_ * w1c;
    float tcr = cr_ * w2c - ci_ * w2s, tci = cr_ * w2s + ci_ * w2c;
    float tdr = dr_ * w3c - di_ * w3s, tdi = dr_ * w3s + di_ * w3c;
    float apc_r = ar_ + tcr, amc_r = ar_ - tcr;
    float apc_i = ai_ + tci, amc_i = ai_ - tci;
    float bpd_r = tbr + tdr, bmd_r = tbr - tdr;
    float bpd_i = tbi + tdi, bmd_i = tbi - tdi;
    re[i0] = apc_r + bpd_r;       im[i0] = apc_i + bpd_i;
    re[i2] = apc_r - bpd_r;       im[i2] = apc_i - bpd_i;
    re[i1] = amc_r - sgn * bmd_i; im[i1] = amc_i + sgn * bmd_r;
    re[i3] = amc_r + sgn * bmd_i; im[i3] = amc_i - sgn * bmd_r;
    __syncthreads();
  }
}

// forward fft2: one block per (Bi,d,c). x2T channel-major -> coalesced loads;
// X stored [(Bi*4+c)*48+d][k] -> coalesced writes.
__global__ __launch_bounds__(256) void fft_fwd(const float* __restrict__ x2T,
    float* __restrict__ Xre, float* __restrict__ Xim) {
  __shared__ float re[1024];
  __shared__ float im[1024];
  __shared__ float twc[768];
  __shared__ float tws[768];
  int blk = blockIdx.x;
  int c = blk & 3;
  int rest = blk >> 2;
  int d = rest % 48, Bi = rest / 48;
  int tid = threadIdx.x;
  for (int k = tid; k < 768; k += 256) {
    float sv, cv;
    __sincosf(-PI_F * (float)k * (1.f / 512.f), &sv, &cv);
    twc[k] = cv; tws[k] = sv;
  }
  const float* pb = x2T + ((size_t)(Bi * 192 + d)) * 1024;
  for (int n = tid; n < 1024; n += 256) {
    float v0 = pb[n];
    float v1 = pb[48 * 1024 + n];
    float v2 = pb[96 * 1024 + n];
    float v3 = pb[144 * 1024 + n];
    float rr, ii;
    if (c == 0)      { rr = v0 + v1 + v2 + v3; ii = 0.f; }
    else if (c == 1) { rr = v0 - v2;           ii = -(v1 - v3); }
    else if (c == 2) { rr = v0 - v1 + v2 - v3; ii = 0.f; }
    else             { rr = v0 - v2;           ii = (v1 - v3); }
    re[n] = rr; im[n] = ii;
  }
  __syncthreads();
  fft1024r4(re, im, twc, tws, tid, -1.0f);
  float* xo_r = Xre + ((size_t)((Bi * 4 + c) * 48 + d)) * 1024;
  float* xo_i = Xim + ((size_t)((Bi * 4 + c) * 48 + d)) * 1024;
  for (int k = tid; k < 1024; k += 256) {
    xo_r[k] = re[k] * (1.f / 64.f);
    xo_i[k] = im[k] * (1.f / 64.f);
  }
}

// ---------------- EinFFT mix, FUSED l1+l2, 4 k-rows per wave ----------------
__global__ __launch_bounds__(256) void mix_fused(float* __restrict__ Xre,
    float* __restrict__ Xim, const float* __restrict__ cw1,
    const float* __restrict__ cw2, const float* __restrict__ cb1,
    const float* __restrict__ cb2) {
  __shared__ float r1s[4][48][4];
  __shared__ float i1s[4][48][4];
  int w = threadIdx.x >> 6;
  int j = threadIdx.x & 63;
  int rg = blockIdx.x * 4 + w;       // [0, 4096)
  int kq = rg & 255;
  int b  = (rg >> 8) & 3;
  int Bi = rg >> 10;
  int k0 = kq * 4;
  size_t xbase = ((size_t)((Bi * 4 + b) * 48)) * 1024 + k0;
  if (j < 48) {
    const float* wr = cw1 + b * 2304;
    const float* wi = cw1 + 9216 + b * 2304;
    float b1r = cb1[b * 48 + j], b1i = cb1[192 + b * 48 + j];
    float ar[4] = {b1r, b1r, b1r, b1r};
    float ai[4] = {b1i, b1i, b1i, b1i};
#pragma unroll 8
    for (int dd = 0; dd < 48; ++dd) {
      float4 xr = *(const float4*)(Xre + xbase + (size_t)dd * 1024);
      float4 xi = *(const float4*)(Xim + xbase + (size_t)dd * 1024);
      float wrv = wr[dd * 48 + j], wiv = wi[dd * 48 + j];
      ar[0] = fmaf(xr.x, wrv, ar[0]); ar[0] = fmaf(-xi.x, wiv, ar[0]);
      ai[0] = fmaf(xr.x, wiv, ai[0]); ai[0] = fmaf(xi.x, wrv, ai[0]);
      ar[1] = fmaf(xr.y, wrv, ar[1]); ar[1] = fmaf(-xi.y, wiv, ar[1]);
      ai[1] = fmaf(xr.y, wiv, ai[1]); ai[1] = fmaf(xi.y, wrv, ai[1]);
      ar[2] = fmaf(xr.z, wrv, ar[2]); ar[2] = fmaf(-xi.z, wiv, ar[2]);
      ai[2] = fmaf(xr.z, wiv, ai[2]); ai[2] = fmaf(xi.z, wrv, ai[2]);
      ar[3] = fmaf(xr.w, wrv, ar[3]); ar[3] = fmaf(-xi.w, wiv, ar[3]);
      ai[3] = fmaf(xr.w, wiv, ai[3]); ai[3] = fmaf(xi.w, wrv, ai[3]);
    }
    float4 r1v, i1v;
    r1v.x = fmaxf(ar[0], 0.f); r1v.y = fmaxf(ar[1], 0.f);
    r1v.z = fmaxf(ar[2], 0.f); r1v.w = fmaxf(ar[3], 0.f);
    i1v.x = fmaxf(ai[0], 0.f); i1v.y = fmaxf(ai[1], 0.f);
    i1v.z = fmaxf(ai[2], 0.f); i1v.w = fmaxf(ai[3], 0.f);
    *(float4*)&r1s[w][j][0] = r1v;
    *(float4*)&i1s[w][j][0] = i1v;
    // same-wave LDS RAW: compiler inserts lgkmcnt wait; no barrier needed
    const float* wr2 = cw2 + b * 2304;
    const float* wi2 = cw2 + 9216 + b * 2304;
    float b2r = cb2[b * 48 + j], b2i = cb2[192 + b * 48 + j];
    float a2r[4] = {b2r, b2r, b2r, b2r};
    float a2i[4] = {b2i, b2i, b2i, b2i};
#pragma unroll 8
    for (int dd = 0; dd < 48; ++dd) {
      float4 rv = *(const float4*)&r1s[w][dd][0];
      float4 iv = *(const float4*)&i1s[w][dd][0];
      float wrv = wr2[dd * 48 + j], wiv = wi2[dd * 48 + j];
      a2r[0] = fmaf(rv.x, wrv, a2r[0]); a2r[0] = fmaf(-iv.x, wiv, a2r[0]);
      a2i[0] = fmaf(rv.x, wiv, a2i[0]); a2i[0] = fmaf(iv.x, wrv, a2i[0]);
      a2r[1] = fmaf(rv.y, wrv, a2r[1]); a2r[1] = fmaf(-iv.y, wiv, a2r[1]);
      a2i[1] = fmaf(rv.y, wiv, a2i[1]); a2i[1] = fmaf(iv.y, wrv, a2i[1]);
      a2r[2] = fmaf(rv.z, wrv, a2r[2]); a2r[2] = fmaf(-iv.z, wiv, a2r[2]);
      a2i[2] = fmaf(rv.z, wiv, a2i[2]); a2i[2] = fmaf(iv.z, wrv, a2i[2]);
      a2r[3] = fmaf(rv.w, wrv, a2r[3]); a2r[3] = fmaf(-iv.w, wiv, a2r[3]);
      a2i[3] = fmaf(rv.w, wiv, a2i[3]); a2i[3] = fmaf(iv.w, wrv, a2i[3]);
    }
    float4 zr, zi;
#pragma unroll
    for (int r = 0; r < 4; ++r) {
      float vr = a2r[r], vi = a2i[r];
      (&zr.x)[r] = (vr > 0.01f) ? vr - 0.01f : ((vr < -0.01f) ? vr + 0.01f : 0.f);
      (&zi.x)[r] = (vi > 0.01f) ? vi - 0.01f : ((vi < -0.01f) ? vi + 0.01f : 0.f);
    }
    size_t obase = ((size_t)((Bi * 4 + b) * 48 + j)) * 1024 + k0;
    *(float4*)(Xre + obase) = zr;
    *(float4*)(Xim + obase) = zi;
  }
}

// inverse fft2: one block per (Bi,d,c). Z layout [(Bi*4+c')*48+d][k] ->
// coalesced reads; inline inverse 4-pt DFT, IFFT, residual, real write.
__global__ __launch_bounds__(256) void fft_inv(const float* __restrict__ Zre,
    const float* __restrict__ Zim, const float* __restrict__ x1, float* __restrict__ out) {
  __shared__ float re[1024];
  __shared__ float im[1024];
  __shared__ float twc[768];
  __shared__ float tws[768];
  int blk = blockIdx.x;
  int c = blk & 3;
  int rest = blk >> 2;
  int d = rest % 48, Bi = rest / 48;
  int tid = threadIdx.x;
  for (int k = tid; k < 768; k += 256) {
    float sv, cv;
    __sincosf(PI_F * (float)k * (1.f / 512.f), &sv, &cv);
    twc[k] = cv; tws[k] = sv;
  }
  const float* zr0 = Zre + ((size_t)((Bi * 4) * 48 + d)) * 1024;
  const float* zi0 = Zim + ((size_t)((Bi * 4) * 48 + d)) * 1024;
  const int cs = 48 * 1024;
  for (int k = tid; k < 1024; k += 256) {
    float r0 = zr0[k], r1v = zr0[cs + k], r2 = zr0[2 * cs + k], r3 = zr0[3 * cs + k];
    float i0 = zi0[k], i1v = zi0[cs + k], i2 = zi0[2 * cs + k], i3 = zi0[3 * cs + k];
    float rr, ii;
    if (c == 0)      { rr = r0 + r1v + r2 + r3;  ii = i0 + i1v + i2 + i3; }
    else if (c == 1) { rr = r0 - i1v - r2 + i3;  ii = i0 + r1v - i2 - r3; }
    else if (c == 2) { rr = r0 - r1v + r2 - r3;  ii = i0 - i1v + i2 - i3; }
    else             { rr = r0 + i1v - r2 - i3;  ii = i0 - r1v - i2 + r3; }
    re[k] = rr; im[k] = ii;
  }
  __syncthreads();
  fft1024r4(re, im, twc, tws, tid, 1.0f);
  for (int n = tid; n < 1024; n += 256) {
    size_t o = (size_t)(Bi * 1024 + n) * 192 + c * 48 + d;
    out[o] = x1[o] + re[n] * (1.f / 64.f);
  }
}

extern "C" void kernel_launch(void* const* d_in, const int* in_sizes, int n_in,
                              void* d_out, int out_size, void* d_ws, size_t ws_size,
                              hipStream_t stream) {
  const float* x         = (const float*)d_in[0];
  const float* ln1_w     = (const float*)d_in[1];
  const float* ln1_b     = (const float*)d_in[2];
  const float* in_proj_w = (const float*)d_in[3];
  const float* conv_w    = (const float*)d_in[4];
  const float* conv_b    = (const float*)d_in[5];
  const float* x_proj_w  = (const float*)d_in[6];
  const float* dt_proj_w = (const float*)d_in[7];
  const float* dt_proj_b = (const float*)d_in[8];
  const float* A_log     = (const float*)d_in[9];
  const float* Dvec      = (const float*)d_in[10];
  const float* out_proj_w= (const float*)d_in[11];
  const float* ln2_w     = (const float*)d_in[12];
  const float* ln2_b     = (const float*)d_in[13];
  const float* cw1       = (const float*)d_in[14];
  const float* cw2       = (const float*)d_in[15];
  const float* cb1       = (const float*)d_in[16];
  const float* cb2       = (const float*)d_in[17];
  float* out = (float*)d_out;
  float* ws  = (float*)d_ws;

  // workspace layout (floats). Aliases:
  //  duT = Xre+Xim region (dead until fft_fwd), dltT in dlt's slot,
  //  x1 = xln; x2T in x2's slot; xcbf lives in xln slot (dead until
  //  gemm_at32m writes x1); xpwbf in x2T slot (dead until ln2t);
  //  opwbf after Xim (fresh region).
  float* xz   = ws;                    // 3145728
  float* xc   = xz  + 3145728;         // 1572864
  float* dbc  = xc  + 1572864;         // 573440
  float* dltT = dbc + 573440;          // 1572864
  float* yvT  = dltT + 1572864;        // 1572864 (TRANSPOSED y: [b][d][t])
  float* xln  = yvT + 1572864;         // 786432
  float* x2T  = xln + 786432;          // 786432 (channel-major: [Bi*192+ch][n])
  float* Xre  = x2T + 786432;          // 786432 (layout [(Bi*4+c)*48+d][k])
  float* Xim  = Xre + 786432;          // 786432
  float* duT = Xre;                    // 1572864 (spans Xre+Xim)
  float* x1 = xln;
  unsigned short* opwbf = (unsigned short*)(Xim + 786432);   // 36864 f-slots
  unsigned short* xcbf  = (unsigned short*)xln;   // 1572864 bf16 = full xln slot
  unsigned short* xpwbf = (unsigned short*)x2T;   // 53760 bf16 (head of x2T slot)

  gemm_ln_in<<<dim3(12, 64), 256, 0, stream>>>(x, ln1_w, ln1_b, in_proj_w, xz);
  conv_silu<<<1536, 256, 0, stream>>>(xz, conv_w, conv_b, xc, xcbf, x_proj_w, xpwbf);
  gemm_mfma_xp<<<dim3(3, 64), 256, 0, stream>>>(xcbf, xpwbf, dbc);
  delta_trans<<<384, 256, 0, stream>>>(dbc, dt_proj_w, dt_proj_b, xc, dltT, duT,
                                       out_proj_w, opwbf);
  scan_single<<<1536, 64, 0, stream>>>(dltT, duT, dbc, A_log, xc, xz, Dvec, yvT);
  gemm_at32m<<<dim3(3, 64), 256, 0, stream>>>(yvT, opwbf, x, x1);
  ln2t_kernel<<<128, 256, 0, stream>>>(x1, ln2_w, ln2_b, x2T);
  fft_fwd<<<768, 256, 0, stream>>>(x2T, Xre, Xim);
  mix_fused<<<1024, 256, 0, stream>>>(Xre, Xim, cw1, cw2, cb1, cb2);
  fft_inv<<<768, 256, 0, stream>>>(Xre, Xim, x1, out);
}

// Round 13
// 291.566 us; speedup vs baseline: 1.0906x; 1.0588x over previous
//
#include <hip/hip_runtime.h>
#include <math.h>

#define PI_F 3.14159265358979323846f

typedef __attribute__((ext_vector_type(8))) short short8v;   // 8 bf16 (4 VGPRs)
typedef __attribute__((ext_vector_type(4))) float f32x4;     // MFMA accumulator

// broadcast lane l's value of v to all lanes (v_readlane -> SGPR)
__device__ __forceinline__ float lane_bcast(float v, int l) {
  return __int_as_float(__builtin_amdgcn_readlane(__float_as_int(v), l));
}

// float -> bf16 (round to nearest even)
__device__ __forceinline__ unsigned short f2bf(float f) {
  unsigned u = __float_as_uint(f);
  unsigned r = u + 0x7FFFu + ((u >> 16) & 1u);
  return (unsigned short)(r >> 16);
}

// ---------------- wave reduce ----------------
__device__ __forceinline__ float wave_reduce_sum(float v) {
  v += __shfl_xor(v, 32, 64);
  v += __shfl_xor(v, 16, 64);
  v += __shfl_xor(v, 8, 64);
  v += __shfl_xor(v, 4, 64);
  v += __shfl_xor(v, 2, 64);
  v += __shfl_xor(v, 1, 64);
  return v;
}

// ---------------- LayerNorm -> bf16 output; fused W cast (R10-proven) ------
__global__ __launch_bounds__(256) void ln_kernel(const float* __restrict__ x,
    const float* __restrict__ w, const float* __restrict__ b,
    const float* __restrict__ ipw, unsigned short* __restrict__ obf,
    unsigned short* __restrict__ wbf) {
  int row = blockIdx.x * 4 + (threadIdx.x >> 6);
  int lane = threadIdx.x & 63;
  const float* xr = x + (size_t)row * 192;
  float v0 = xr[lane], v1 = xr[lane + 64], v2 = xr[lane + 128];
  float s  = wave_reduce_sum(v0 + v1 + v2);
  float s2 = wave_reduce_sum(v0 * v0 + v1 * v1 + v2 * v2);
  float mu  = s * (1.f / 192.f);
  float var = s2 * (1.f / 192.f) - mu * mu;
  float rs  = rsqrtf(var + 1e-5f);
  unsigned short* orow = obf + (size_t)row * 192;
  orow[lane]       = f2bf((v0 - mu) * rs * w[lane]       + b[lane]);
  orow[lane + 64]  = f2bf((v1 - mu) * rs * w[lane + 64]  + b[lane + 64]);
  orow[lane + 128] = f2bf((v2 - mu) * rs * w[lane + 128] + b[lane + 128]);
  // fused cast of in_proj_w (147456 = 1024 blocks * 144)
  for (int i = threadIdx.x; i < 144; i += 256) {
    int idx = blockIdx.x * 144 + i;
    wbf[idx] = f2bf(ipw[idx]);
  }
}

// ---------------- MFMA bf16 GEMM: xz = A(4096x192) @ W(768x192)^T -----------
__global__ __launch_bounds__(256) void gemm_mfma_in(
    const unsigned short* __restrict__ Abf, const unsigned short* __restrict__ Wbf,
    float* __restrict__ C) {
  int wave = threadIdx.x >> 6;
  int lane = threadIdx.x & 63;
  int m0 = blockIdx.y * 64 + wave * 16;
  int n0 = blockIdx.x * 64;
  int rw = lane & 15;
  int g  = lane >> 4;
  const unsigned short* Ap = Abf + (size_t)(m0 + rw) * 192 + g * 8;
  const unsigned short* Wp = Wbf + (size_t)(n0 + rw) * 192 + g * 8;
  f32x4 acc[4];
#pragma unroll
  for (int f = 0; f < 4; ++f) acc[f] = (f32x4){0.f, 0.f, 0.f, 0.f};
#pragma unroll
  for (int kk = 0; kk < 192; kk += 32) {
    short8v a = *(const short8v*)(Ap + kk);
#pragma unroll
    for (int f = 0; f < 4; ++f) {
      short8v bfr = *(const short8v*)(Wp + (size_t)f * 16 * 192 + kk);
      acc[f] = __builtin_amdgcn_mfma_f32_16x16x32_bf16(a, bfr, acc[f], 0, 0, 0);
    }
  }
#pragma unroll
  for (int f = 0; f < 4; ++f)
#pragma unroll
    for (int r = 0; r < 4; ++r)
      C[(size_t)(m0 + g * 4 + r) * 768 + n0 + f * 16 + rw] = acc[f][r];
}

// ---------------- MFMA bf16 GEMM: dbc = xc(4096x384) @ x_proj_w(140x384)^T --
__global__ __launch_bounds__(256) void gemm_mfma_xp(
    const unsigned short* __restrict__ Abf, const unsigned short* __restrict__ Wbf,
    float* __restrict__ C) {
  int wave = threadIdx.x >> 6;
  int lane = threadIdx.x & 63;
  int m0 = blockIdx.y * 64 + wave * 16;
  int n0 = blockIdx.x * 64;
  int rw = lane & 15;
  int g  = lane >> 4;
  const unsigned short* Ap = Abf + (size_t)(m0 + rw) * 384 + g * 8;
  f32x4 acc[4];
#pragma unroll
  for (int f = 0; f < 4; ++f) acc[f] = (f32x4){0.f, 0.f, 0.f, 0.f};
  short8v bz = {0, 0, 0, 0, 0, 0, 0, 0};
#pragma unroll
  for (int kk = 0; kk < 384; kk += 32) {
    short8v a = *(const short8v*)(Ap + kk);
#pragma unroll
    for (int f = 0; f < 4; ++f) {
      int n = n0 + f * 16 + rw;
      short8v bfr = (n < 140)
        ? *(const short8v*)(Wbf + (size_t)n * 384 + g * 8 + kk) : bz;
      acc[f] = __builtin_amdgcn_mfma_f32_16x16x32_bf16(a, bfr, acc[f], 0, 0, 0);
    }
  }
#pragma unroll
  for (int f = 0; f < 4; ++f)
#pragma unroll
    for (int r = 0; r < 4; ++r) {
      int n = n0 + f * 16 + rw;
      if (n < 140)
        C[(size_t)(m0 + g * 4 + r) * 140 + n] = acc[f][r];
    }
}

// ---------------- MFMA bf16 GEMM with k-major A (LDS transpose) -------------
__global__ __launch_bounds__(256) void gemm_at32m(const float* __restrict__ AT,
    const unsigned short* __restrict__ Wbf, const float* __restrict__ res,
    float* __restrict__ C) {
  __shared__ unsigned As[64][17];   // [m][k-pair], stride 17 => bank-conflict-free
  int tid = threadIdx.x;
  int wave = tid >> 6, lane = tid & 63;
  int n0 = blockIdx.x * 64;         // 0,64,128
  int m0 = blockIdx.y * 64;         // 64 blocks
  int bb = m0 >> 10;
  int t0 = m0 & 1023;
  const float* Ab = AT + ((size_t)bb * 384) * 1024 + t0;
  int col = tid & 63;               // m within tile (t)
  int kq  = tid >> 6;               // 0..3 (k-pair group)
  int rw = lane & 15, g = lane >> 4;
  f32x4 acc[4];
#pragma unroll
  for (int f = 0; f < 4; ++f) acc[f] = (f32x4){0.f, 0.f, 0.f, 0.f};
#pragma unroll
  for (int kk = 0; kk < 384; kk += 32) {
#pragma unroll
    for (int p = 0; p < 4; ++p) {
      int k2 = kq + p * 4;                       // u32 index 0..15
      int k = kk + k2 * 2;
      float f0 = Ab[(size_t)k * 1024 + col];
      float f1 = Ab[(size_t)(k + 1) * 1024 + col];
      As[col][k2] = (unsigned)f2bf(f0) | ((unsigned)f2bf(f1) << 16);
    }
    __syncthreads();
    int mrow = wave * 16 + rw;
    unsigned u0 = As[mrow][g * 4 + 0];
    unsigned u1 = As[mrow][g * 4 + 1];
    unsigned u2 = As[mrow][g * 4 + 2];
    unsigned u3 = As[mrow][g * 4 + 3];
    short8v a;
    ((unsigned*)&a)[0] = u0; ((unsigned*)&a)[1] = u1;
    ((unsigned*)&a)[2] = u2; ((unsigned*)&a)[3] = u3;
#pragma unroll
    for (int f = 0; f < 4; ++f) {
      short8v bfr = *(const short8v*)(Wbf + (size_t)(n0 + f * 16 + rw) * 384 + kk + g * 8);
      acc[f] = __builtin_amdgcn_mfma_f32_16x16x32_bf16(a, bfr, acc[f], 0, 0, 0);
    }
    __syncthreads();
  }
#pragma unroll
  for (int f = 0; f < 4; ++f)
#pragma unroll
    for (int r = 0; r < 4; ++r) {
      int m = m0 + wave * 16 + g * 4 + r;
      int n = n0 + f * 16 + rw;
      C[(size_t)m * 192 + n] = acc[f][r] + res[(size_t)m * 192 + n];
    }
}

// ---------------- transposing LayerNorm: writes x2T[(Bi*192+ch)*1024 + n] ----
__global__ __launch_bounds__(256) void ln2t_kernel(const float* __restrict__ x,
    const float* __restrict__ w, const float* __restrict__ b, float* __restrict__ xT) {
  __shared__ float xt[32][193];
  __shared__ float mu_s[32], rs_s[32];
  int blk = blockIdx.x;            // 128 blocks
  int Bi = blk >> 5;
  int t0 = (blk & 31) * 32;
  int tid = threadIdx.x;
  const float* xb = x + ((size_t)(Bi * 1024 + t0)) * 192;
  for (int i = tid; i < 32 * 192; i += 256) {
    xt[i / 192][i % 192] = xb[i];
  }
  __syncthreads();
  int row = tid >> 3, seg = tid & 7;
  float s = 0.f, s2 = 0.f;
  const float* xr = &xt[row][seg * 24];
#pragma unroll
  for (int k = 0; k < 24; ++k) { float v = xr[k]; s += v; s2 += v * v; }
  s  += __shfl_xor(s, 1, 64);  s  += __shfl_xor(s, 2, 64);  s  += __shfl_xor(s, 4, 64);
  s2 += __shfl_xor(s2, 1, 64); s2 += __shfl_xor(s2, 2, 64); s2 += __shfl_xor(s2, 4, 64);
  if (seg == 0) {
    float mu = s * (1.f / 192.f);
    float var = s2 * (1.f / 192.f) - mu * mu;
    mu_s[row] = mu;
    rs_s[row] = rsqrtf(var + 1e-5f);
  }
  __syncthreads();
  for (int i = tid; i < 32 * 192; i += 256) {
    int ch = i >> 5, r2 = i & 31;
    float v = (xt[r2][ch] - mu_s[r2]) * rs_s[r2] * w[ch] + b[ch];
    xT[((size_t)(Bi * 192 + ch)) * 1024 + t0 + r2] = v;
  }
}

// ---------------- causal depthwise conv1d(k=4) + SiLU + bf16 copy ----------
__global__ __launch_bounds__(256) void conv_silu(const float* __restrict__ xz,
    const float* __restrict__ cw, const float* __restrict__ cb,
    float* __restrict__ xc, unsigned short* __restrict__ xcbf,
    const float* __restrict__ xpw, unsigned short* __restrict__ xpwbf) {
  // fused cast of x_proj_w (53760 = 1536 blocks * 35)
  if (threadIdx.x < 35) {
    int ci = blockIdx.x * 35 + threadIdx.x;
    xpwbf[ci] = f2bf(xpw[ci]);
  }
  int e4 = blockIdx.x * 256 + threadIdx.x;   // [0, 393216)
  if (e4 >= 4 * 1024 * 96) return;
  int d4 = e4 % 96;
  int t  = (e4 / 96) % 1024;
  int b  = e4 / (96 * 1024);
  int d = d4 * 4;
  const float* base = xz + (size_t)(b * 1024) * 768 + d;
  float4 acc = *(const float4*)(cb + d);
  const float4* cwv = (const float4*)(cw + d * 4);
  float4 c0 = cwv[0], c1 = cwv[1], c2 = cwv[2], c3 = cwv[3];
#pragma unroll
  for (int j = 0; j < 4; ++j) {
    int tt = t - 3 + j;
    if (tt >= 0) {
      float4 v = *(const float4*)(base + (size_t)tt * 768);
      float w0 = (&c0.x)[j], w1 = (&c1.x)[j], w2 = (&c2.x)[j], w3 = (&c3.x)[j];
      acc.x = fmaf(v.x, w0, acc.x);
      acc.y = fmaf(v.y, w1, acc.y);
      acc.z = fmaf(v.z, w2, acc.z);
      acc.w = fmaf(v.w, w3, acc.w);
    }
  }
  float4 o;
  o.x = acc.x / (1.f + __expf(-acc.x));
  o.y = acc.y / (1.f + __expf(-acc.y));
  o.z = acc.z / (1.f + __expf(-acc.z));
  o.w = acc.w / (1.f + __expf(-acc.w));
  size_t idx = ((size_t)(b * 1024 + t) * 384) + d;
  *(float4*)(xc + idx) = o;
  uint2 pk;
  pk.x = (unsigned)f2bf(o.x) | ((unsigned)f2bf(o.y) << 16);
  pk.y = (unsigned)f2bf(o.z) | ((unsigned)f2bf(o.w) << 16);
  *(uint2*)(xcbf + idx) = pk;
}

// ---------------- delta + transpose: dltT[b,d,t], duT[b,d,t] = dlt*xc ------
// Also casts out_proj_w to bf16 (384 blocks * 192 = 73728).
__global__ __launch_bounds__(256) void delta_trans(const float* __restrict__ dbc,
    const float* __restrict__ dtw, const float* __restrict__ dtb,
    const float* __restrict__ xc, float* __restrict__ dltT, float* __restrict__ duT,
    const float* __restrict__ opw, unsigned short* __restrict__ opwbf) {
  __shared__ float dts[64][13];
  __shared__ float xt[64][65];
  int blk = blockIdx.x;           // 4 * 16 * 6 = 384
  int b  = blk / 96;
  int rem = blk % 96;
  int tt = rem / 6, dd = rem % 6;
  int t0 = tt * 64, d0 = dd * 64;
  int tid = threadIdx.x;
  for (int i = tid; i < 192; i += 256) {
    int idx = blk * 192 + i;
    opwbf[idx] = f2bf(opw[idx]);
  }
  for (int i = tid; i < 64 * 12; i += 256) {
    int tl = i / 12, r = i % 12;
    dts[tl][r] = dbc[((size_t)b * 1024 + t0 + tl) * 140 + r];
  }
  {
    int col = tid & 63, rg = tid >> 6;
#pragma unroll
    for (int j = 0; j < 16; ++j) {
      int row = j * 4 + rg;
      xt[row][col] = xc[((size_t)b * 1024 + t0 + row) * 384 + d0 + col];
    }
  }
  __syncthreads();
  int tl = tid & 63, grp = tid >> 6;
#pragma unroll
  for (int j = 0; j < 16; ++j) {
    int dl = grp * 16 + j;
    int d = d0 + dl;
    float s = dtb[d];
#pragma unroll
    for (int r = 0; r < 12; ++r) s += dts[tl][r] * dtw[d * 12 + r];
    float dlt = (s > 20.f) ? s : log1pf(__expf(s));
    size_t ob = ((size_t)b * 384 + d) * 1024 + t0 + tl;
    dltT[ob] = dlt;
    duT[ob]  = dlt * xt[tl][dl];
  }
}

// ---------------- SINGLE-PASS selective scan, SOFTWARE-PIPELINED ----------
// Accepted plateau (R2/R10: ~93 us, noise band 93-99).
#define SCAN_GBODY(G, BC, CC, XCV, ZVV, BN, CN, XCN, ZVN)                  \
  {                                                                        \
    int ts_ = (G) * 16;                                                    \
    if ((G) + 1 < 64) {                                                    \
      int tn_ = ts_ + 16;                                                  \
      _Pragma("unroll")                                                    \
      for (int i = 0; i < 16; ++i) {                                       \
        size_t ro = (size_t)(tn_ + i) * 140;                               \
        BN[i] = Bp[ro]; CN[i] = Cp[ro];                                    \
      }                                                                    \
      if (lane < 16) { XCN = xcp[(size_t)(tn_ + lane) * 384];              \
                       ZVN = xzp[(size_t)(tn_ + lane) * 768]; }            \
      if (((G) & 3) == 2) {                                                \
        int sn_ = ((G) >> 2) + 1;                                          \
        if (sn_ < 16) { dvN = dT[sn_ * 64 + lane];                         \
                        duN = uT[sn_ * 64 + lane]; }                       \
      }                                                                    \
    }                                                                      \
    int tb_ = ts_ & 63;                                                    \
    _Pragma("unroll")                                                      \
    for (int i = 0; i < 16; ++i) {                                         \
      float sdv = lane_bcast(dvC, tb_ + i);                                \
      float sdu = lane_bcast(duC, tb_ + i);                                \
      float a = exp2f(sdv * A);                                            \
      h = fmaf(h, a, sdu * BC[i]);                                         \
      tile[i][lane] = h * CC[i];                                           \
    }                                                                      \
    const float* trow_ = &tile[tq][q * 16];                                \
    float s_ = 0.f;                                                        \
    _Pragma("unroll")                                                      \
    for (int i = 0; i < 16; ++i) s_ += trow_[i];                           \
    s_ += __shfl_xor(s_, 16, 64);                                          \
    s_ += __shfl_xor(s_, 32, 64);                                          \
    if (lane < 16) {                                                       \
      float sg_ = ZVV / (1.f + __expf(-ZVV));                              \
      yp[ts_ + lane] = (s_ + XCV * ddv) * sg_;                             \
    }                                                                      \
    if (((G) & 3) == 3) { dvC = dvN; duC = duN; }                          \
  }

__global__ __launch_bounds__(64, 1) void scan_single(const float* __restrict__ dltT,
    const float* __restrict__ duT, const float* __restrict__ dbc,
    const float* __restrict__ A_log, const float* __restrict__ xc,
    const float* __restrict__ xz, const float* __restrict__ Dvec,
    float* __restrict__ yT) {
  __shared__ float tile[16][65];
  int bd = blockIdx.x;             // 1536 = 4 * 384
  int b = bd / 384, d = bd % 384;
  int lane = threadIdx.x;          // = state index n
  float A = -__expf(A_log[d * 64 + lane]) * 1.44269504f;
  const float* dT = dltT + ((size_t)b * 384 + d) * 1024;
  const float* uT = duT  + ((size_t)b * 384 + d) * 1024;
  const float* Bp = dbc + ((size_t)b * 1024) * 140 + 12 + lane;
  const float* Cp = Bp + 64;
  float ddv = Dvec[d];
  float* yp = yT + ((size_t)b * 384 + d) * 1024;
  const float* xcp = xc + ((size_t)b * 1024) * 384 + d;
  const float* xzp = xz + ((size_t)b * 1024) * 768 + 384 + d;
  int tq = lane & 15;
  int q  = lane >> 4;
  float h = 0.f;

  float Ba[16], Ca[16], Bb[16], Cb[16];
  float dvC, duC, dvN = 0.f, duN = 0.f;
  float xcA = 0.f, zvA = 0.f, xcB = 0.f, zvB = 0.f;

  // ---- prologue: seg-0 dv/du, group-0 B/C and gate loads ----
  dvC = dT[lane];
  duC = uT[lane];
#pragma unroll
  for (int i = 0; i < 16; ++i) {
    size_t ro = (size_t)i * 140;
    Ba[i] = Bp[ro];
    Ca[i] = Cp[ro];
  }
  if (lane < 16) {
    xcA = xcp[(size_t)lane * 384];
    zvA = xzp[(size_t)lane * 768];
  }

  for (int gp = 0; gp < 32; ++gp) {
    int g0 = gp * 2;
    SCAN_GBODY(g0,     Ba, Ca, xcA, zvA, Bb, Cb, xcB, zvB)
    SCAN_GBODY(g0 + 1, Bb, Cb, xcB, zvB, Ba, Ca, xcA, zvA)
  }
}

// ---------------- radix-4 1024-pt FFT in LDS ----------------
__device__ __forceinline__ int rev4_10(int i) {
  unsigned r = __brev((unsigned)i) >> 22;
  return (int)(((r & 0x155u) << 1) | ((r >> 1) & 0x155u));
}

__device__ __forceinline__ void fft1024r4(float* __restrict__ re,
    float* __restrict__ im, const float* __restrict__ twc,
    const float* __restrict__ tws, int tid, float sgn) {
  for (int i = tid; i < 1024; i += 256) {
    int r = rev4_10(i);
    if (i < r) {
      float t = re[i]; re[i] = re[r]; re[r] = t;
      t = im[i]; im[i] = im[r]; im[r] = t;
    }
  }
  __syncthreads();
  {
    float4 ar = *(float4*)&re[tid * 4];
    float4 ai = *(float4*)&im[tid * 4];
    float apc_r = ar.x + ar.z, amc_r = ar.x - ar.z;
    float apc_i = ai.x + ai.z, amc_i = ai.x - ai.z;
    float bpd_r = ar.y + ar.w, bmd_r = ar.y - ar.w;
    float bpd_i = ai.y + ai.w, bmd_i = ai.y - ai.w;
    float4 yr, yi;
    yr.x = apc_r + bpd_r;        yi.x = apc_i + bpd_i;
    yr.z = apc_r - bpd_r;        yi.z = apc_i - bpd_i;
    yr.y = amc_r - sgn * bmd_i;  yi.y = amc_i + sgn * bmd_r;
    yr.w = amc_r + sgn * bmd_i;  yi.w = amc_i - sgn * bmd_r;
    *(float4*)&re[tid * 4] = yr;
    *(float4*)&im[tid * 4] = yi;
  }
  __syncthreads();
#pragma unroll
  for (int s = 1; s < 5; ++s) {
    int L = 1 << (2 * s);
    int tstep = 256 >> (2 * s);
    int j = tid & (L - 1);
    int base = ((tid >> (2 * s)) << (2 * s + 2)) + j;
    int i0 = base, i1 = base + L, i2 = base + 2 * L, i3 = base + 3 * L;
    int x1i = j * tstep;
    float w1c = twc[x1i],     w1s = tws[x1i];
    float w2c = twc[2 * x1i], w2s = tws[2 * x1i];
    float w3c = twc[3 * x1i], w3s = tws[3 * x1i];
    float ar_ = re[i0], ai_ = im[i0];
    float br_ = re[i1], bi_ = im[i1];
    float cr_ = re[i2], ci_ = im[i2];
    float dr_ = re[i3], di_ = im[i3];
    float tbr = br_ * w1c - bi_ * w1s, tbi = br_ * w1s + bi_ * w1c;
    float tcr = cr_ * w2c - ci_ * w2s, tci = cr_ * w2s + ci_ * w2c;
    float tdr = dr_ * w3c - di_ * w3s, tdi = dr_ * w3s + di_ * w3c;
    float apc_r = ar_ + tcr, amc_r = ar_ - tcr;
    float apc_i = ai_ + tci, amc_i = ai_ - tci;
    float bpd_r = tbr + tdr, bmd_r = tbr - tdr;
    float bpd_i = tbi + tdi, bmd_i = tbi - tdi;
    re[i0] = apc_r + bpd_r;       im[i0] = apc_i + bpd_i;
    re[i2] = apc_r - bpd_r;       im[i2] = apc_i - bpd_i;
    re[i1] = amc_r - sgn * bmd_i; im[i1] = amc_i + sgn * bmd_r;
    re[i3] = amc_r + sgn * bmd_i; im[i3] = amc_i - sgn * bmd_r;
    __syncthreads();
  }
}

// forward fft2, HALVED: 384 blocks (was 768) exploiting real input symmetry.
// The 4-pt c-DFT of REAL x2 gives: c0,c2 channels REAL -> packed as ONE
// complex FFT (z=F0+i*F2; untangle X0=(Z[k]+conj(Z[N-k]))/2,
// X2=-i(Z[k]-conj(Z[N-k]))/2); c3 input = conj(c1 input) -> X3[k] =
// conj(X1[(N-k)%N]) free. Half the FFTs AND half the HBM reads; exact math.
__global__ __launch_bounds__(256) void fft_fwd(const float* __restrict__ x2T,
    float* __restrict__ Xre, float* __restrict__ Xim) {
  __shared__ float re[1024];
  __shared__ float im[1024];
  __shared__ float twc[768];
  __shared__ float tws[768];
  int blk = blockIdx.x;            // 384 = 4Bi * 48d * 2unit
  int unit = blk & 1;
  int rest = blk >> 1;
  int d = rest % 48, Bi = rest / 48;
  int tid = threadIdx.x;
  for (int k = tid; k < 768; k += 256) {
    float sv, cv;
    __sincosf(-PI_F * (float)k * (1.f / 512.f), &sv, &cv);
    twc[k] = cv; tws[k] = sv;
  }
  const float* pb = x2T + ((size_t)(Bi * 192 + d)) * 1024;
  for (int n = tid; n < 1024; n += 256) {
    float v0 = pb[n];
    float v1 = pb[48 * 1024 + n];
    float v2 = pb[96 * 1024 + n];
    float v3 = pb[144 * 1024 + n];
    float rr, ii;
    if (unit == 0) { rr = v0 + v1 + v2 + v3; ii = v0 - v1 + v2 - v3; } // F0 + i*F2
    else           { rr = v0 - v2;           ii = -(v1 - v3); }       // c = 1
    re[n] = rr; im[n] = ii;
  }
  __syncthreads();
  fft1024r4(re, im, twc, tws, tid, -1.0f);
  if (unit == 0) {
    float* r0 = Xre + ((size_t)((Bi * 4 + 0) * 48 + d)) * 1024;
    float* i0 = Xim + ((size_t)((Bi * 4 + 0) * 48 + d)) * 1024;
    float* r2 = Xre + ((size_t)((Bi * 4 + 2) * 48 + d)) * 1024;
    float* i2 = Xim + ((size_t)((Bi * 4 + 2) * 48 + d)) * 1024;
    for (int k = tid; k < 1024; k += 256) {
      int nk = (1024 - k) & 1023;
      float zr = re[k], zi = im[k];
      float yr = re[nk], yi = im[nk];
      r0[k] = (zr + yr) * (0.5f / 64.f);
      i0[k] = (zi - yi) * (0.5f / 64.f);
      r2[k] = (zi + yi) * (0.5f / 64.f);
      i2[k] = (yr - zr) * (0.5f / 64.f);
    }
  } else {
    float* r1 = Xre + ((size_t)((Bi * 4 + 1) * 48 + d)) * 1024;
    float* i1 = Xim + ((size_t)((Bi * 4 + 1) * 48 + d)) * 1024;
    float* r3 = Xre + ((size_t)((Bi * 4 + 3) * 48 + d)) * 1024;
    float* i3 = Xim + ((size_t)((Bi * 4 + 3) * 48 + d)) * 1024;
    for (int k = tid; k < 1024; k += 256) {
      int nk = (1024 - k) & 1023;
      r1[k] = re[k] * (1.f / 64.f);
      i1[k] = im[k] * (1.f / 64.f);
      r3[k] = re[nk] * (1.f / 64.f);
      i3[k] = -im[nk] * (1.f / 64.f);
    }
  }
}

// ---------------- EinFFT mix, FUSED l1+l2, 4 k-rows per wave ----------------
__global__ __launch_bounds__(256) void mix_fused(float* __restrict__ Xre,
    float* __restrict__ Xim, const float* __restrict__ cw1,
    const float* __restrict__ cw2, const float* __restrict__ cb1,
    const float* __restrict__ cb2) {
  __shared__ float r1s[4][48][4];
  __shared__ float i1s[4][48][4];
  int w = threadIdx.x >> 6;
  int j = threadIdx.x & 63;
  int rg = blockIdx.x * 4 + w;       // [0, 4096)
  int kq = rg & 255;
  int b  = (rg >> 8) & 3;
  int Bi = rg >> 10;
  int k0 = kq * 4;
  size_t xbase = ((size_t)((Bi * 4 + b) * 48)) * 1024 + k0;
  if (j < 48) {
    const float* wr = cw1 + b * 2304;
    const float* wi = cw1 + 9216 + b * 2304;
    float b1r = cb1[b * 48 + j], b1i = cb1[192 + b * 48 + j];
    float ar[4] = {b1r, b1r, b1r, b1r};
    float ai[4] = {b1i, b1i, b1i, b1i};
#pragma unroll 8
    for (int dd = 0; dd < 48; ++dd) {
      float4 xr = *(const float4*)(Xre + xbase + (size_t)dd * 1024);
      float4 xi = *(const float4*)(Xim + xbase + (size_t)dd * 1024);
      float wrv = wr[dd * 48 + j], wiv = wi[dd * 48 + j];
      ar[0] = fmaf(xr.x, wrv, ar[0]); ar[0] = fmaf(-xi.x, wiv, ar[0]);
      ai[0] = fmaf(xr.x, wiv, ai[0]); ai[0] = fmaf(xi.x, wrv, ai[0]);
      ar[1] = fmaf(xr.y, wrv, ar[1]); ar[1] = fmaf(-xi.y, wiv, ar[1]);
      ai[1] = fmaf(xr.y, wiv, ai[1]); ai[1] = fmaf(xi.y, wrv, ai[1]);
      ar[2] = fmaf(xr.z, wrv, ar[2]); ar[2] = fmaf(-xi.z, wiv, ar[2]);
      ai[2] = fmaf(xr.z, wiv, ai[2]); ai[2] = fmaf(xi.z, wrv, ai[2]);
      ar[3] = fmaf(xr.w, wrv, ar[3]); ar[3] = fmaf(-xi.w, wiv, ar[3]);
      ai[3] = fmaf(xr.w, wiv, ai[3]); ai[3] = fmaf(xi.w, wrv, ai[3]);
    }
    float4 r1v, i1v;
    r1v.x = fmaxf(ar[0], 0.f); r1v.y = fmaxf(ar[1], 0.f);
    r1v.z = fmaxf(ar[2], 0.f); r1v.w = fmaxf(ar[3], 0.f);
    i1v.x = fmaxf(ai[0], 0.f); i1v.y = fmaxf(ai[1], 0.f);
    i1v.z = fmaxf(ai[2], 0.f); i1v.w = fmaxf(ai[3], 0.f);
    *(float4*)&r1s[w][j][0] = r1v;
    *(float4*)&i1s[w][j][0] = i1v;
    // same-wave LDS RAW: compiler inserts lgkmcnt wait; no barrier needed
    const float* wr2 = cw2 + b * 2304;
    const float* wi2 = cw2 + 9216 + b * 2304;
    float b2r = cb2[b * 48 + j], b2i = cb2[192 + b * 48 + j];
    float a2r[4] = {b2r, b2r, b2r, b2r};
    float a2i[4] = {b2i, b2i, b2i, b2i};
#pragma unroll 8
    for (int dd = 0; dd < 48; ++dd) {
      float4 rv = *(const float4*)&r1s[w][dd][0];
      float4 iv = *(const float4*)&i1s[w][dd][0];
      float wrv = wr2[dd * 48 + j], wiv = wi2[dd * 48 + j];
      a2r[0] = fmaf(rv.x, wrv, a2r[0]); a2r[0] = fmaf(-iv.x, wiv, a2r[0]);
      a2i[0] = fmaf(rv.x, wiv, a2i[0]); a2i[0] = fmaf(iv.x, wrv, a2i[0]);
      a2r[1] = fmaf(rv.y, wrv, a2r[1]); a2r[1] = fmaf(-iv.y, wiv, a2r[1]);
      a2i[1] = fmaf(rv.y, wiv, a2i[1]); a2i[1] = fmaf(iv.y, wrv, a2i[1]);
      a2r[2] = fmaf(rv.z, wrv, a2r[2]); a2r[2] = fmaf(-iv.z, wiv, a2r[2]);
      a2i[2] = fmaf(rv.z, wiv, a2i[2]); a2i[2] = fmaf(iv.z, wrv, a2i[2]);
      a2r[3] = fmaf(rv.w, wrv, a2r[3]); a2r[3] = fmaf(-iv.w, wiv, a2r[3]);
      a2i[3] = fmaf(rv.w, wiv, a2i[3]); a2i[3] = fmaf(iv.w, wrv, a2i[3]);
    }
    float4 zr, zi;
#pragma unroll
    for (int r = 0; r < 4; ++r) {
      float vr = a2r[r], vi = a2i[r];
      (&zr.x)[r] = (vr > 0.01f) ? vr - 0.01f : ((vr < -0.01f) ? vr + 0.01f : 0.f);
      (&zi.x)[r] = (vi > 0.01f) ? vi - 0.01f : ((vi < -0.01f) ? vi + 0.01f : 0.f);
    }
    size_t obase = ((size_t)((Bi * 4 + b) * 48 + j)) * 1024 + k0;
    *(float4*)(Xre + obase) = zr;
    *(float4*)(Xim + obase) = zi;
  }
}

// inverse fft2: one block per (Bi,d,c). Z layout [(Bi*4+c')*48+d][k] ->
// coalesced reads; inline inverse 4-pt DFT, IFFT, residual, real write.
__global__ __launch_bounds__(256) void fft_inv(const float* __restrict__ Zre,
    const float* __restrict__ Zim, const float* __restrict__ x1, float* __restrict__ out) {
  __shared__ float re[1024];
  __shared__ float im[1024];
  __shared__ float twc[768];
  __shared__ float tws[768];
  int blk = blockIdx.x;
  int c = blk & 3;
  int rest = blk >> 2;
  int d = rest % 48, Bi = rest / 48;
  int tid = threadIdx.x;
  for (int k = tid; k < 768; k += 256) {
    float sv, cv;
    __sincosf(PI_F * (float)k * (1.f / 512.f), &sv, &cv);
    twc[k] = cv; tws[k] = sv;
  }
  const float* zr0 = Zre + ((size_t)((Bi * 4) * 48 + d)) * 1024;
  const float* zi0 = Zim + ((size_t)((Bi * 4) * 48 + d)) * 1024;
  const int cs = 48 * 1024;
  for (int k = tid; k < 1024; k += 256) {
    float r0 = zr0[k], r1v = zr0[cs + k], r2 = zr0[2 * cs + k], r3 = zr0[3 * cs + k];
    float i0 = zi0[k], i1v = zi0[cs + k], i2 = zi0[2 * cs + k], i3 = zi0[3 * cs + k];
    float rr, ii;
    if (c == 0)      { rr = r0 + r1v + r2 + r3;  ii = i0 + i1v + i2 + i3; }
    else if (c == 1) { rr = r0 - i1v - r2 + i3;  ii = i0 + r1v - i2 - r3; }
    else if (c == 2) { rr = r0 - r1v + r2 - r3;  ii = i0 - i1v + i2 - i3; }
    else             { rr = r0 + i1v - r2 - i3;  ii = i0 - r1v - i2 + r3; }
    re[k] = rr; im[k] = ii;
  }
  __syncthreads();
  fft1024r4(re, im, twc, tws, tid, 1.0f);
  for (int n = tid; n < 1024; n += 256) {
    size_t o = (size_t)(Bi * 1024 + n) * 192 + c * 48 + d;
    out[o] = x1[o] + re[n] * (1.f / 64.f);
  }
}

extern "C" void kernel_launch(void* const* d_in, const int* in_sizes, int n_in,
                              void* d_out, int out_size, void* d_ws, size_t ws_size,
                              hipStream_t stream) {
  const float* x         = (const float*)d_in[0];
  const float* ln1_w     = (const float*)d_in[1];
  const float* ln1_b     = (const float*)d_in[2];
  const float* in_proj_w = (const float*)d_in[3];
  const float* conv_w    = (const float*)d_in[4];
  const float* conv_b    = (const float*)d_in[5];
  const float* x_proj_w  = (const float*)d_in[6];
  const float* dt_proj_w = (const float*)d_in[7];
  const float* dt_proj_b = (const float*)d_in[8];
  const float* A_log     = (const float*)d_in[9];
  const float* Dvec      = (const float*)d_in[10];
  const float* out_proj_w= (const float*)d_in[11];
  const float* ln2_w     = (const float*)d_in[12];
  const float* ln2_b     = (const float*)d_in[13];
  const float* cw1       = (const float*)d_in[14];
  const float* cw2       = (const float*)d_in[15];
  const float* cb1       = (const float*)d_in[16];
  const float* cb2       = (const float*)d_in[17];
  float* out = (float*)d_out;
  float* ws  = (float*)d_ws;

  // workspace layout (floats). Aliases (R10-proven):
  //  duT = Xre+Xim region (dead until fft_fwd), dltT in dlt's slot,
  //  x1 = xln; x2T in x2's slot; xcbf in xln slot (dead until gemm_at32m
  //  writes x1); xpwbf in x2T slot (dead until ln2t); xbf/wbf/opwbf after Xim.
  float* xz   = ws;                    // 3145728
  float* xc   = xz  + 3145728;         // 1572864
  float* dbc  = xc  + 1572864;         // 573440
  float* dltT = dbc + 573440;          // 1572864
  float* yvT  = dltT + 1572864;        // 1572864 (TRANSPOSED y: [b][d][t])
  float* xln  = yvT + 1572864;         // 786432
  float* x2T  = xln + 786432;          // 786432 (channel-major: [Bi*192+ch][n])
  float* Xre  = x2T + 786432;          // 786432 (layout [(Bi*4+c)*48+d][k])
  float* Xim  = Xre + 786432;          // 786432
  float* duT = Xre;                    // 1572864 (spans Xre+Xim)
  float* x1 = xln;
  unsigned short* xbf = (unsigned short*)(Xim + 786432);            // 393216 f-slots
  unsigned short* wbf = (unsigned short*)(Xim + 786432 + 393216);   // 36864 f-slots
  unsigned short* opwbf = (unsigned short*)(Xim + 786432 + 393216 + 36864); // 36864 f-slots
  unsigned short* xcbf  = (unsigned short*)xln;   // 1572864 bf16 = full xln slot
  unsigned short* xpwbf = (unsigned short*)x2T;   // 53760 bf16 (head of x2T slot)

  ln_kernel<<<1024, 256, 0, stream>>>(x, ln1_w, ln1_b, in_proj_w, xbf, wbf);
  gemm_mfma_in<<<dim3(12, 64), 256, 0, stream>>>(xbf, wbf, xz);
  conv_silu<<<1536, 256, 0, stream>>>(xz, conv_w, conv_b, xc, xcbf, x_proj_w, xpwbf);
  gemm_mfma_xp<<<dim3(3, 64), 256, 0, stream>>>(xcbf, xpwbf, dbc);
  delta_trans<<<384, 256, 0, stream>>>(dbc, dt_proj_w, dt_proj_b, xc, dltT, duT,
                                       out_proj_w, opwbf);
  scan_single<<<1536, 64, 0, stream>>>(dltT, duT, dbc, A_log, xc, xz, Dvec, yvT);
  gemm_at32m<<<dim3(3, 64), 256, 0, stream>>>(yvT, opwbf, x, x1);
  ln2t_kernel<<<128, 256, 0, stream>>>(x1, ln2_w, ln2_b, x2T);
  fft_fwd<<<384, 256, 0, stream>>>(x2T, Xre, Xim);
  mix_fused<<<1024, 256, 0, stream>>>(Xre, Xim, cw1, cw2, cb1, cb2);
  fft_inv<<<768, 256, 0, stream>>>(Xre, Xim, x1, out);
}